// Round 4
// baseline (340.209 us; speedup 1.0000x reference)
//
#include <hip/hip_runtime.h>

typedef unsigned short u16;
typedef __bf16 bf16x8 __attribute__((ext_vector_type(8)));
typedef float f32x4 __attribute__((ext_vector_type(4)));

union U8 { ushort4 h4[2]; uint4 q; bf16x8 v; };

__device__ __forceinline__ u16 f2bf(float f) {
    union { float f; unsigned int u; } v; v.f = f;
    unsigned int u = v.u;
    unsigned int r = (u + 0x7FFFu + ((u >> 16) & 1u)) >> 16;
    return (u16)r;
}
__device__ __forceinline__ float lrelu(float x) { return x > 0.f ? x : 0.01f * x; }

__device__ __forceinline__ f32x4 mfma_(bf16x8 a, bf16x8 b, f32x4 c) {
    return __builtin_amdgcn_mfma_f32_16x16x32_bf16(a, b, c, 0, 0, 0);
}

__device__ __forceinline__ float wred64(float s) {
    s += __shfl_xor(s, 1); s += __shfl_xor(s, 2); s += __shfl_xor(s, 4);
    s += __shfl_xor(s, 8); s += __shfl_xor(s, 16); s += __shfl_xor(s, 32);
    return s;
}

// ---------------- Kernel A: the two 32768x256 mat-vecs (HBM-bound) -----------
__global__ __launch_bounds__(256) void big_matvec(
    const float* __restrict__ Wp, const float* __restrict__ bp,
    const float* __restrict__ Wgp, const float* __restrict__ bgp,
    const float* __restrict__ psf, const float* __restrict__ pgf,
    float* __restrict__ cat, float* __restrict__ pg) {
    const int wave = blockIdx.x * 4 + (threadIdx.x >> 6);
    const int NW = gridDim.x * 4;
    const int l = threadIdx.x & 63;
    float4 xa = *(const float4*)(psf + l * 4);
    float4 xg = *(const float4*)(pgf + l * 4);
    for (int r = wave; r < 32768; r += NW) {   // cf rows
        float4 w = *(const float4*)(Wp + (size_t)r * 256 + l * 4);
        float s = wred64(w.x * xa.x + w.y * xa.y + w.z * xa.z + w.w * xa.w);
        if (l == 0) cat[(r >> 8) * 768 + (r & 255)] = lrelu(s + bp[r]);
    }
    for (int r = wave; r < 32768; r += NW) {   // pg rows
        float4 w = *(const float4*)(Wgp + (size_t)r * 256 + l * 4);
        float s = wred64(w.x * xg.x + w.y * xg.y + w.z * xg.z + w.w * xg.w);
        if (l == 0) pg[r] = lrelu(s + bgp[r]);
    }
}

// ------- Stage1: wave-per-channel fused mat-vecs over all per-node heads -----
// channel space: [0,256) P | [256,512) Q | [512,768) An | [768,1024) Bn |
//                [1024,1280) geo-pre | [1280,1337) sem | [1337,1347) semins |
//                1347 exists.  grid = 128 nodes x 2 halves, 512 threads.
__global__ __launch_bounds__(512) void stage1(
    const float* __restrict__ cat, const float* __restrict__ pgin,
    const float* __restrict__ Wel,
    const float* __restrict__ Wgc, const float* __restrict__ bgc,
    const float* __restrict__ gw, const float* __restrict__ gb,
    const float* __restrict__ We, const float* __restrict__ be,
    const float* __restrict__ Ws, const float* __restrict__ bs,
    const float* __restrict__ Wsi, const float* __restrict__ bsi,
    const float* __restrict__ Wne0,
    float* __restrict__ P, float* __restrict__ Q,
    float* __restrict__ An, float* __restrict__ Bn, int* __restrict__ ok,
    float* __restrict__ o_geo, float* __restrict__ o_sem,
    float* __restrict__ o_semins, float* __restrict__ o_exists) {
    __shared__ float geo_s[256];
    const int i = blockIdx.x >> 1, half = blockIdx.x & 1;
    const int tid = threadIdx.x;
    const int wv = tid >> 6, l = tid & 63;
    float4 xa = *(const float4*)(cat + i * 768 + l * 4);
    float4 xg = *(const float4*)(pgin + i * 256 + l * 4);
    const int cbase = half * 674;
    for (int c = cbase + wv; c < cbase + 674; c += 8) {
        const float* wr;
        float4 x = xa;
        if (c < 256)       wr = Wel + (size_t)c * 512;
        else if (c < 512)  wr = Wel + (size_t)(c - 256) * 512 + 256;
        else if (c < 768)  wr = Wne0 + (size_t)(c - 512) * 772;
        else if (c < 1024) wr = Wne0 + (size_t)(c - 768) * 772 + 256;
        else if (c < 1280) { wr = Wgc + (size_t)(c - 1024) * 256; x = xg; }
        else if (c < 1337) wr = Ws + (size_t)(c - 1280) * 256;
        else if (c < 1347) wr = Wsi + (size_t)(c - 1337) * 256;
        else               wr = We;
        float4 w = *(const float4*)(wr + l * 4);
        float s = wred64(w.x * x.x + w.y * x.y + w.z * x.z + w.w * x.w);
        if (l == 0) {
            if (c < 256)       P[i * 256 + c] = s;
            else if (c < 512)  Q[i * 256 + c - 256] = s;
            else if (c < 768)  An[i * 256 + c - 512] = s;
            else if (c < 1024) Bn[i * 256 + c - 768] = s;
            else if (c < 1280) geo_s[c - 1024] = s + bgc[c - 1024];
            else if (c < 1337) o_sem[i * 57 + c - 1280] = s + bs[c - 1280];
            else if (c < 1347) o_semins[i * 10 + c - 1337] = s + bsi[c - 1337];
            else {
                float e = s + be[0];
                o_exists[i] = e;
                ok[i] = (e > 0.f) ? 1 : 0;
            }
        }
    }
    __syncthreads();
    if (half == 1 && tid < 256) {
        // group-norm: 32 groups of 8 consecutive channels (within-wave lanes)
        float g = geo_s[tid];
        float s = g;
        s += __shfl_xor(s, 1); s += __shfl_xor(s, 2); s += __shfl_xor(s, 4);
        float m = s * 0.125f;
        float d = g - m;
        float q2 = d * d;
        q2 += __shfl_xor(q2, 1); q2 += __shfl_xor(q2, 2); q2 += __shfl_xor(q2, 4);
        float var = q2 * 0.125f;
        float xn = d / sqrtf(var + 1e-5f);
        o_geo[i * 256 + tid] = lrelu(xn * gw[tid] + gb[tid]);
    }
}

// ---------- Edge stage: el = lrelu(P_i + Q_j + bel), edge_logits -------------
__global__ __launch_bounds__(256) void edge_k(
    const float* __restrict__ P, const float* __restrict__ Q,
    const float* __restrict__ bel, const float* __restrict__ Wee,
    const float* __restrict__ bee,
    u16* __restrict__ el, float* __restrict__ o_edge) {
    const int pair = blockIdx.x * 4 + (threadIdx.x >> 6);
    const int l = threadIdx.x & 63;
    const int i = pair >> 7, j = pair & 127;
    float4 p = *(const float4*)(P + i * 256 + l * 4);
    float4 q = *(const float4*)(Q + j * 256 + l * 4);
    float4 b = *(const float4*)(bel + l * 4);
    float e0 = lrelu(p.x + q.x + b.x);
    float e1 = lrelu(p.y + q.y + b.y);
    float e2 = lrelu(p.z + q.z + b.z);
    float e3 = lrelu(p.w + q.w + b.w);
    ushort4 st; st.x = f2bf(e0); st.y = f2bf(e1); st.z = f2bf(e2); st.w = f2bf(e3);
    *(ushort4*)(el + (size_t)pair * 256 + l * 4) = st;
    float4 w;
    w = *(const float4*)(Wee + 0 * 256 + l * 4);
    float a0 = e0 * w.x + e1 * w.y + e2 * w.z + e3 * w.w;
    w = *(const float4*)(Wee + 1 * 256 + l * 4);
    float a1 = e0 * w.x + e1 * w.y + e2 * w.z + e3 * w.w;
    w = *(const float4*)(Wee + 2 * 256 + l * 4);
    float a2 = e0 * w.x + e1 * w.y + e2 * w.z + e3 * w.w;
    w = *(const float4*)(Wee + 3 * 256 + l * 4);
    float a3 = e0 * w.x + e1 * w.y + e2 * w.z + e3 * w.w;
#pragma unroll
    for (int mk = 1; mk < 64; mk <<= 1) {
        a0 += __shfl_xor(a0, mk); a1 += __shfl_xor(a1, mk);
        a2 += __shfl_xor(a2, mk); a3 += __shfl_xor(a3, mk);
    }
    if (l == 0) {
        float4 o;
        o.x = a0 + bee[0]; o.y = a1 + bee[1];
        o.z = a2 + bee[2]; o.w = a3 + bee[3];
        *(float4*)(o_edge + (size_t)pair * 4) = o;
    }
}

// ---------- Pack W3 (Wne cols 512..767) into MFMA fragment order, bf16 -------
// fragment id r = wid*2048 + nt*512 + ks*64 + lane ; 2 iterations.
__global__ __launch_bounds__(256) void pack_k(
    const float* __restrict__ Wne, u16* __restrict__ W3p) {
    const int tg = blockIdx.x * 256 + threadIdx.x;   // 0..16383
    const int it = tg >> 13;
    const int r = tg & 8191;
    const int wid = r >> 11, nt = (r >> 9) & 3, ks = (r >> 6) & 7, l = r & 63;
    const int lr = l & 15, lq = l >> 4;
    const int h = wid * 64 + nt * 16 + lr;
    const int k0 = ks * 32 + lq * 8;
    const float* src = Wne + (size_t)it * 256 * 772 + (size_t)h * 772 + 512 + k0;
    float4 a = *(const float4*)src;
    float4 b = *(const float4*)(src + 4);
    U8 u;
    u.h4[0].x = f2bf(a.x); u.h4[0].y = f2bf(a.y);
    u.h4[0].z = f2bf(a.z); u.h4[0].w = f2bf(a.w);
    u.h4[1].x = f2bf(b.x); u.h4[1].y = f2bf(b.y);
    u.h4[1].z = f2bf(b.z); u.h4[1].w = f2bf(b.w);
    ((uint4*)W3p)[tg] = u.q;
}

// ---------- Node transform iteration 1: An/Bn from x1 (wave-per-channel) -----
__global__ __launch_bounds__(512) void node_k(
    const float* __restrict__ cat, int xoff,
    const float* __restrict__ Wne_it,
    float* __restrict__ An, float* __restrict__ Bn) {
    const int i = blockIdx.x >> 1, half = blockIdx.x & 1;
    const int wv = threadIdx.x >> 6, l = threadIdx.x & 63;
    float4 x = *(const float4*)(cat + i * 768 + xoff + l * 4);
    const int cbase = half * 256;
    for (int c = cbase + wv; c < cbase + 256; c += 8) {
        const float* wr = (c < 256) ? (Wne_it + (size_t)c * 772)
                                    : (Wne_it + (size_t)(c - 256) * 772 + 256);
        float4 w = *(const float4*)(wr + l * 4);
        float s = wred64(w.x * x.x + w.y * x.y + w.z * x.z + w.w * x.w);
        if (l == 0) {
            if (c < 256) An[i * 256 + c] = s;
            else         Bn[i * 256 + c - 256] = s;
        }
    }
}

// ---------- Message passing: E = el@W3^T via MFMA, fused max-reduce ----------
__global__ __launch_bounds__(256) void mp_k(
    const u16* __restrict__ el, const float* __restrict__ An,
    const float* __restrict__ Bn, const float* __restrict__ Wne_it,
    const float* __restrict__ bne_it, const u16* __restrict__ W3p_it,
    const float* __restrict__ logits,
    const int* __restrict__ ok, float* __restrict__ xout /* stride 768 */) {
    const int i = blockIdx.x;
    const int tid = threadIdx.x;
    if (!ok[i]) { xout[i * 768 + tid] = 0.f; return; }
    const int l = tid & 63, wid = tid >> 6;
    const int lr = l & 15, lq = l >> 4;
    const int h0 = wid * 64;

    bf16x8 bfr[4][8];
    float an[4], bnev[4];
    float4 w4[4];
#pragma unroll
    for (int nt = 0; nt < 4; ++nt) {
#pragma unroll
        for (int ks = 0; ks < 8; ++ks) {
            U8 u;
            u.q = ((const uint4*)W3p_it)[(wid * 4 + nt) * 8 * 64 + ks * 64 + l];
            bfr[nt][ks] = u.v;
        }
        const int h = h0 + nt * 16 + lr;
        an[nt] = An[i * 256 + h];
        bnev[nt] = bne_it[h];
        w4[nt] = *(const float4*)(Wne_it + (size_t)h * 772 + 768);
    }
    // active-group mask from ok[] via ballot
    unsigned long long b1 = __ballot(ok[l] != 0);
    unsigned long long b2 = __ballot(ok[64 + l] != 0);
    unsigned actmask = 0;
#pragma unroll
    for (int jc = 0; jc < 4; ++jc) {
        if ((b1 >> (jc * 16)) & 0xFFFFull) actmask |= (1u << jc);
        if ((b2 >> (jc * 16)) & 0xFFFFull) actmask |= (1u << (4 + jc));
    }
    float rm0 = -1e30f, rm1 = -1e30f, rm2 = -1e30f, rm3 = -1e30f;
    for (int jc = 0; jc < 8; ++jc) {
        if (!(actmask & (1u << jc))) continue;
        f32x4 acc0{0.f, 0.f, 0.f, 0.f}, acc1{0.f, 0.f, 0.f, 0.f};
        f32x4 acc2{0.f, 0.f, 0.f, 0.f}, acc3{0.f, 0.f, 0.f, 0.f};
#pragma unroll
        for (int ks = 0; ks < 8; ++ks) {
            U8 u;
            u.q = *(const uint4*)(el + (size_t)(i * 128 + jc * 16 + lr) * 256 + ks * 32 + lq * 8);
            bf16x8 af = u.v;
            acc0 = mfma_(af, bfr[0][ks], acc0);
            acc1 = mfma_(af, bfr[1][ks], acc1);
            acc2 = mfma_(af, bfr[2][ks], acc2);
            acc3 = mfma_(af, bfr[3][ks], acc3);
        }
#pragma unroll
        for (int r = 0; r < 4; ++r) {
            const int j = jc * 16 + lq * 4 + r;
            if (!ok[j]) continue;
            float4 lg = *(const float4*)(logits + (size_t)(i * 128 + j) * 4);
            bool any = (lg.x > 0.f) | (lg.y > 0.f) | (lg.z > 0.f) | (lg.w > 0.f);
            if (!any) continue;
            float b0 = Bn[j * 256 + h0 + 0 * 16 + lr];
            float b1v = Bn[j * 256 + h0 + 1 * 16 + lr];
            float b2v = Bn[j * 256 + h0 + 2 * 16 + lr];
            float b3 = Bn[j * 256 + h0 + 3 * 16 + lr];
            float amx0 = -1e30f, amx1 = -1e30f, amx2 = -1e30f, amx3 = -1e30f;
            if (lg.x > 0.f) {
                amx0 = fmaxf(amx0, w4[0].x * lg.x); amx1 = fmaxf(amx1, w4[1].x * lg.x);
                amx2 = fmaxf(amx2, w4[2].x * lg.x); amx3 = fmaxf(amx3, w4[3].x * lg.x);
            }
            if (lg.y > 0.f) {
                amx0 = fmaxf(amx0, w4[0].y * lg.y); amx1 = fmaxf(amx1, w4[1].y * lg.y);
                amx2 = fmaxf(amx2, w4[2].y * lg.y); amx3 = fmaxf(amx3, w4[3].y * lg.y);
            }
            if (lg.z > 0.f) {
                amx0 = fmaxf(amx0, w4[0].z * lg.z); amx1 = fmaxf(amx1, w4[1].z * lg.z);
                amx2 = fmaxf(amx2, w4[2].z * lg.z); amx3 = fmaxf(amx3, w4[3].z * lg.z);
            }
            if (lg.w > 0.f) {
                amx0 = fmaxf(amx0, w4[0].w * lg.w); amx1 = fmaxf(amx1, w4[1].w * lg.w);
                amx2 = fmaxf(amx2, w4[2].w * lg.w); amx3 = fmaxf(amx3, w4[3].w * lg.w);
            }
            rm0 = fmaxf(rm0, lrelu(acc0[r] + an[0] + b0 + bnev[0] + amx0));
            rm1 = fmaxf(rm1, lrelu(acc1[r] + an[1] + b1v + bnev[1] + amx1));
            rm2 = fmaxf(rm2, lrelu(acc2[r] + an[2] + b2v + bnev[2] + amx2));
            rm3 = fmaxf(rm3, lrelu(acc3[r] + an[3] + b3 + bnev[3] + amx3));
        }
    }
    rm0 = fmaxf(rm0, __shfl_xor(rm0, 16)); rm0 = fmaxf(rm0, __shfl_xor(rm0, 32));
    rm1 = fmaxf(rm1, __shfl_xor(rm1, 16)); rm1 = fmaxf(rm1, __shfl_xor(rm1, 32));
    rm2 = fmaxf(rm2, __shfl_xor(rm2, 16)); rm2 = fmaxf(rm2, __shfl_xor(rm2, 32));
    rm3 = fmaxf(rm3, __shfl_xor(rm3, 16)); rm3 = fmaxf(rm3, __shfl_xor(rm3, 32));
    if (lq == 0) {
        xout[i * 768 + h0 + 0 * 16 + lr] = fmaxf(rm0, 0.f);
        xout[i * 768 + h0 + 1 * 16 + lr] = fmaxf(rm1, 0.f);
        xout[i * 768 + h0 + 2 * 16 + lr] = fmaxf(rm2, 0.f);
        xout[i * 768 + h0 + 3 * 16 + lr] = fmaxf(rm3, 0.f);
    }
}

// ---------- Final head: two-phase wave-per-channel -------------------------
__global__ __launch_bounds__(1024) void head_k(
    const float* __restrict__ cat, const float* __restrict__ Wc,
    const float* __restrict__ bc, const float* __restrict__ Wc2,
    const float* __restrict__ bc2, float* __restrict__ o_child) {
    __shared__ float ch_s[256];
    const int i = blockIdx.x;
    const int wv = threadIdx.x >> 6, l = threadIdx.x & 63;
    // phase 1: ch = lrelu(cat_i @ Wc^T + bc), K = 768
    float4 x0 = *(const float4*)(cat + i * 768 + l * 12);
    float4 x1 = *(const float4*)(cat + i * 768 + l * 12 + 4);
    float4 x2 = *(const float4*)(cat + i * 768 + l * 12 + 8);
    for (int c = wv; c < 256; c += 16) {
        const float* wr = Wc + (size_t)c * 768 + l * 12;
        float4 w0 = *(const float4*)wr;
        float4 w1 = *(const float4*)(wr + 4);
        float4 w2 = *(const float4*)(wr + 8);
        float s = w0.x * x0.x + w0.y * x0.y + w0.z * x0.z + w0.w * x0.w
                + w1.x * x1.x + w1.y * x1.y + w1.z * x1.z + w1.w * x1.w
                + w2.x * x2.x + w2.y * x2.y + w2.z * x2.z + w2.w * x2.w;
        s = wred64(s);
        if (l == 0) ch_s[c] = lrelu(s + bc[c]);
    }
    __syncthreads();
    // phase 2: child = lrelu(ch @ Wc2^T + bc2), K = 256
    float4 y = *(const float4*)(ch_s + l * 4);
    for (int c = wv; c < 256; c += 16) {
        float4 w = *(const float4*)(Wc2 + (size_t)c * 256 + l * 4);
        float s = wred64(w.x * y.x + w.y * y.y + w.z * y.z + w.w * y.w);
        if (l == 0) o_child[i * 256 + c] = lrelu(s + bc2[c]);
    }
}

extern "C" void kernel_launch(void* const* d_in, const int* in_sizes, int n_in,
                              void* d_out, int out_size, void* d_ws, size_t ws_size,
                              hipStream_t stream) {
    (void)in_sizes; (void)n_in; (void)out_size; (void)ws_size;
    const float* psf = (const float*)d_in[0];
    const float* pgf = (const float*)d_in[1];
    const float* Wp  = (const float*)d_in[2];
    const float* bp  = (const float*)d_in[3];
    const float* We  = (const float*)d_in[4];
    const float* be  = (const float*)d_in[5];
    const float* Ws  = (const float*)d_in[6];
    const float* bs  = (const float*)d_in[7];
    const float* Wsi = (const float*)d_in[8];
    const float* bsi = (const float*)d_in[9];
    const float* Wel = (const float*)d_in[10];
    const float* bel = (const float*)d_in[11];
    const float* Wee = (const float*)d_in[12];
    const float* bee = (const float*)d_in[13];
    const float* Wne = (const float*)d_in[14];
    const float* bne = (const float*)d_in[15];
    const float* Wc  = (const float*)d_in[16];
    const float* bc  = (const float*)d_in[17];
    const float* Wc2 = (const float*)d_in[18];
    const float* bc2 = (const float*)d_in[19];
    const float* Wgc = (const float*)d_in[20];
    const float* bgc = (const float*)d_in[21];
    const float* Wgp = (const float*)d_in[22];
    const float* bgp = (const float*)d_in[23];
    const float* gw  = (const float*)d_in[24];
    const float* gb  = (const float*)d_in[25];

    float* ws  = (float*)d_ws;
    float* pg  = ws;                 // 32768 f32
    float* cat = ws + 32768;         // 128 x 768 f32 (x0|x1|x2)
    float* P   = ws + 131072;        // 32768 f32 (reused as W3p after edge_k)
    float* Q   = ws + 163840;        // 32768 f32 (reused as W3p after edge_k)
    float* An  = ws + 196608;        // 32768 f32
    float* Bn  = ws + 229376;        // 32768 f32
    int*   ok  = (int*)(ws + 262144);    // 128 int
    u16*   el  = (u16*)(ws + 262272);    // 16384 x 256 bf16 (8.39 MB)
    u16*   W3p = (u16*)P;                // 2 x 8192 frags x 16B = 256 KB

    float* out = (float*)d_out;
    float* o_child  = out;
    float* o_geo    = out + 32768;
    float* o_sem    = out + 65536;
    float* o_semins = out + 72832;
    float* o_exists = out + 74112;
    float* o_edge   = out + 74240;

    big_matvec<<<2048, 256, 0, stream>>>(Wp, bp, Wgp, bgp, psf, pgf, cat, pg);
    stage1<<<256, 512, 0, stream>>>(cat, pg, Wel, Wgc, bgc, gw, gb, We, be,
                                    Ws, bs, Wsi, bsi, Wne,
                                    P, Q, An, Bn, ok,
                                    o_geo, o_sem, o_semins, o_exists);
    edge_k<<<4096, 256, 0, stream>>>(P, Q, bel, Wee, bee, el, o_edge);
    pack_k<<<64, 256, 0, stream>>>(Wne, W3p);   // P/Q dead from here on
    mp_k<<<128, 256, 0, stream>>>(el, An, Bn, Wne, bne, W3p,
                                  o_edge, ok, cat + 256);
    node_k<<<256, 512, 0, stream>>>(cat, 256, Wne + 256 * 772, An, Bn);
    mp_k<<<128, 256, 0, stream>>>(el, An, Bn, Wne + 256 * 772, bne + 256,
                                  W3p + 8192 * 8, o_edge, ok, cat + 512);
    head_k<<<128, 1024, 0, stream>>>(cat, Wc, bc, Wc2, bc2, o_child);
}

// Round 6
// 241.630 us; speedup vs baseline: 1.4080x; 1.4080x over previous
//
#include <hip/hip_runtime.h>

typedef unsigned short u16;
typedef __bf16 bf16x8 __attribute__((ext_vector_type(8)));
typedef float f32x4 __attribute__((ext_vector_type(4)));

union U8 { ushort4 h4[2]; uint4 q; bf16x8 v; };

__device__ __forceinline__ u16 f2bf(float f) {
    union { float f; unsigned int u; } v; v.f = f;
    unsigned int u = v.u;
    unsigned int r = (u + 0x7FFFu + ((u >> 16) & 1u)) >> 16;
    return (u16)r;
}
__device__ __forceinline__ float lrelu(float x) { return x > 0.f ? x : 0.01f * x; }

__device__ __forceinline__ f32x4 mfma_(bf16x8 a, bf16x8 b, f32x4 c) {
    return __builtin_amdgcn_mfma_f32_16x16x32_bf16(a, b, c, 0, 0, 0);
}

// ---------------- pack_all: W^T transposes (fp32) + W3 MFMA-frag pack (bf16) -
// blocks: [0,80) WT_a | [80,96) WT_g | [96,128) WT_n | [128,176) WT_c |
//         [176,192) WT_c2 | [192,256) W3p
__global__ __launch_bounds__(256) void pack_all(
    const float* __restrict__ Wel, const float* __restrict__ Wne,
    const float* __restrict__ Ws, const float* __restrict__ Wsi,
    const float* __restrict__ We, const float* __restrict__ Wgc,
    const float* __restrict__ Wc, const float* __restrict__ Wc2,
    float* __restrict__ WT_a, float* __restrict__ WT_g,
    float* __restrict__ WT_n, float* __restrict__ WT_c,
    float* __restrict__ WT_c2, u16* __restrict__ W3p) {
    const int b = blockIdx.x, tid = threadIdx.x;
    if (b >= 192) {  // W3 fragment pack (validated in round 3/4)
        const int tg = (b - 192) * 256 + tid;   // 0..16383
        const int it = tg >> 13;
        const int r = tg & 8191;
        const int wid = r >> 11, nt = (r >> 9) & 3, ks = (r >> 6) & 7, l = r & 63;
        const int lr = l & 15, lq = l >> 4;
        const int h = wid * 64 + nt * 16 + lr;
        const int k0 = ks * 32 + lq * 8;
        const float* src = Wne + (size_t)it * 256 * 772 + (size_t)h * 772 + 512 + k0;
        f32x4 a = *(const f32x4*)src;
        f32x4 c = *(const f32x4*)(src + 4);
        U8 u;
        u.h4[0].x = f2bf(a[0]); u.h4[0].y = f2bf(a[1]);
        u.h4[0].z = f2bf(a[2]); u.h4[0].w = f2bf(a[3]);
        u.h4[1].x = f2bf(c[0]); u.h4[1].y = f2bf(c[1]);
        u.h4[1].z = f2bf(c[2]); u.h4[1].w = f2bf(c[3]);
        ((uint4*)W3p)[tg] = u.q;
        return;
    }
    __shared__ float lds[64][65];
    const int lane = tid & 63, sub = tid >> 6;
    int src_id, ct, kt; float* dst; int ldd;
    if (b < 80)       { src_id = 0; ct = b >> 2;        kt = b & 3;        dst = WT_a;  ldd = 1280; }
    else if (b < 96)  { src_id = 1; ct = (b - 80) >> 2; kt = (b - 80) & 3; dst = WT_g;  ldd = 256; }
    else if (b < 128) { src_id = 2; ct = (b - 96) >> 2; kt = (b - 96) & 3; dst = WT_n;  ldd = 512; }
    else if (b < 176) { src_id = 3; ct = (b - 128) / 12; kt = (b - 128) % 12; dst = WT_c; ldd = 256; }
    else              { src_id = 4; ct = (b - 176) >> 2; kt = (b - 176) & 3; dst = WT_c2; ldd = 256; }
    const int c0 = ct * 64, k0 = kt * 64;
#pragma unroll 4
    for (int p = 0; p < 16; ++p) {
        const int row = p * 4 + sub;
        const int cabs = c0 + row;
        const float* base = nullptr;
        if (src_id == 0) {
            if (cabs < 256)       base = Wel + (size_t)cabs * 512;
            else if (cabs < 512)  base = Wel + (size_t)(cabs - 256) * 512 + 256;
            else if (cabs < 768)  base = Wne + (size_t)(cabs - 512) * 772;
            else if (cabs < 1024) base = Wne + (size_t)(cabs - 768) * 772 + 256;
            else if (cabs < 1081) base = Ws + (size_t)(cabs - 1024) * 256;
            else if (cabs < 1091) base = Wsi + (size_t)(cabs - 1081) * 256;
            else if (cabs == 1091) base = We;
        } else if (src_id == 1) {
            base = Wgc + (size_t)cabs * 256;
        } else if (src_id == 2) {
            base = (cabs < 256) ? Wne + 256 * 772 + (size_t)cabs * 772
                                : Wne + 256 * 772 + (size_t)(cabs - 256) * 772 + 256;
        } else if (src_id == 3) {
            base = Wc + (size_t)cabs * 768;
        } else {
            base = Wc2 + (size_t)cabs * 256;
        }
        lds[row][lane] = base ? base[k0 + lane] : 0.f;
    }
    __syncthreads();
#pragma unroll 4
    for (int p = 0; p < 16; ++p) {
        const int kr = p * 4 + sub;
        dst[(size_t)(k0 + kr) * ldd + c0 + lane] = lds[lane][kr];
    }
}

// ---------------- big_matvec: 4 rows/wave, interleaved reduce chains ---------
__global__ __launch_bounds__(256) void big_matvec(
    const float* __restrict__ Wp, const float* __restrict__ bp,
    const float* __restrict__ Wgp, const float* __restrict__ bgp,
    const float* __restrict__ psf, const float* __restrict__ pgf,
    float* __restrict__ cat, float* __restrict__ pg) {
    const int wg = blockIdx.x * 4 + (threadIdx.x >> 6);  // 0..8191
    const int l = threadIdx.x & 63;
    f32x4 xa = *(const f32x4*)(psf + l * 4);
    f32x4 xg = *(const f32x4*)(pgf + l * 4);
    {
        const int r0 = wg * 4;
        f32x4 w0 = *(const f32x4*)(Wp + (size_t)r0 * 256 + l * 4);
        f32x4 w1 = *(const f32x4*)(Wp + (size_t)(r0 + 1) * 256 + l * 4);
        f32x4 w2 = *(const f32x4*)(Wp + (size_t)(r0 + 2) * 256 + l * 4);
        f32x4 w3 = *(const f32x4*)(Wp + (size_t)(r0 + 3) * 256 + l * 4);
        float s0 = w0[0]*xa[0] + w0[1]*xa[1] + w0[2]*xa[2] + w0[3]*xa[3];
        float s1 = w1[0]*xa[0] + w1[1]*xa[1] + w1[2]*xa[2] + w1[3]*xa[3];
        float s2 = w2[0]*xa[0] + w2[1]*xa[1] + w2[2]*xa[2] + w2[3]*xa[3];
        float s3 = w3[0]*xa[0] + w3[1]*xa[1] + w3[2]*xa[2] + w3[3]*xa[3];
#pragma unroll
        for (int m = 1; m < 64; m <<= 1) {
            s0 += __shfl_xor(s0, m); s1 += __shfl_xor(s1, m);
            s2 += __shfl_xor(s2, m); s3 += __shfl_xor(s3, m);
        }
        if (l == 0) {
            f32x4 bv = *(const f32x4*)(bp + r0);
            f32x4 o; o[0] = lrelu(s0 + bv[0]); o[1] = lrelu(s1 + bv[1]);
            o[2] = lrelu(s2 + bv[2]); o[3] = lrelu(s3 + bv[3]);
            *(f32x4*)(cat + (r0 >> 8) * 768 + (r0 & 255)) = o;
        }
    }
    {
        const int r0 = wg * 4;
        f32x4 w0 = *(const f32x4*)(Wgp + (size_t)r0 * 256 + l * 4);
        f32x4 w1 = *(const f32x4*)(Wgp + (size_t)(r0 + 1) * 256 + l * 4);
        f32x4 w2 = *(const f32x4*)(Wgp + (size_t)(r0 + 2) * 256 + l * 4);
        f32x4 w3 = *(const f32x4*)(Wgp + (size_t)(r0 + 3) * 256 + l * 4);
        float s0 = w0[0]*xg[0] + w0[1]*xg[1] + w0[2]*xg[2] + w0[3]*xg[3];
        float s1 = w1[0]*xg[0] + w1[1]*xg[1] + w1[2]*xg[2] + w1[3]*xg[3];
        float s2 = w2[0]*xg[0] + w2[1]*xg[1] + w2[2]*xg[2] + w2[3]*xg[3];
        float s3 = w3[0]*xg[0] + w3[1]*xg[1] + w3[2]*xg[2] + w3[3]*xg[3];
#pragma unroll
        for (int m = 1; m < 64; m <<= 1) {
            s0 += __shfl_xor(s0, m); s1 += __shfl_xor(s1, m);
            s2 += __shfl_xor(s2, m); s3 += __shfl_xor(s3, m);
        }
        if (l == 0) {
            f32x4 bv = *(const f32x4*)(bgp + r0);
            f32x4 o; o[0] = lrelu(s0 + bv[0]); o[1] = lrelu(s1 + bv[1]);
            o[2] = lrelu(s2 + bv[2]); o[3] = lrelu(s3 + bv[3]);
            *(f32x4*)(pg + r0) = o;
        }
    }
}

// ---------------- stage1_gemv: split-K register GEMV, 4 nodes/block ----------
// blockIdx = g*6 + ct;  ct 0:P 1:Q 2:An0 3:Bn0 4:heads 5:geo
__global__ __launch_bounds__(256) void stage1_gemv(
    const float* __restrict__ cat, const float* __restrict__ pgin,
    const float* __restrict__ WT_a, const float* __restrict__ WT_g,
    const float* __restrict__ bgc, const float* __restrict__ gw,
    const float* __restrict__ gb, const float* __restrict__ be,
    const float* __restrict__ bs, const float* __restrict__ bsi,
    float* __restrict__ P, float* __restrict__ Q,
    float* __restrict__ An, float* __restrict__ Bn, int* __restrict__ ok,
    float* __restrict__ o_geo, float* __restrict__ o_sem,
    float* __restrict__ o_semins, float* __restrict__ o_exists) {
    const int ct = blockIdx.x % 6, g = blockIdx.x / 6;
    const int tid = threadIdx.x, lane = tid & 63, w = tid >> 6;
    __shared__ float xs[4][256];
    __shared__ float part[4][4][256];
    const float* WT; int ldw, c0;
    if (ct == 5) { WT = WT_g; ldw = 256; c0 = 0; }
    else         { WT = WT_a; ldw = 1280; c0 = ct * 256; }
    for (int idx = tid; idx < 1024; idx += 256) {
        const int nn = idx >> 8, k = idx & 255;
        xs[nn][k] = (ct == 5) ? pgin[(g * 4 + nn) * 256 + k]
                              : cat[(g * 4 + nn) * 768 + k];
    }
    __syncthreads();
    f32x4 a0{0,0,0,0}, a1{0,0,0,0}, a2{0,0,0,0}, a3{0,0,0,0};
    const float* wp = WT + (size_t)(w * 64) * ldw + c0 + lane * 4;
#pragma unroll 4
    for (int kk = 0; kk < 64; ++kk) {
        const int k = w * 64 + kk;
        f32x4 wv = *(const f32x4*)wp; wp += ldw;
        a0 += wv * xs[0][k];
        a1 += wv * xs[1][k];
        a2 += wv * xs[2][k];
        a3 += wv * xs[3][k];
    }
    *(f32x4*)&part[w][0][lane * 4] = a0;
    *(f32x4*)&part[w][1][lane * 4] = a1;
    *(f32x4*)&part[w][2][lane * 4] = a2;
    *(f32x4*)&part[w][3][lane * 4] = a3;
    __syncthreads();
    const int c = tid;
    float v[4];
#pragma unroll
    for (int nn = 0; nn < 4; ++nn)
        v[nn] = part[0][nn][c] + part[1][nn][c] + part[2][nn][c] + part[3][nn][c];
    if (ct < 4) {
        float* dst = (ct == 0) ? P : (ct == 1) ? Q : (ct == 2) ? An : Bn;
#pragma unroll
        for (int nn = 0; nn < 4; ++nn) dst[(g * 4 + nn) * 256 + c] = v[nn];
    } else if (ct == 4) {
        if (c < 57) {
#pragma unroll
            for (int nn = 0; nn < 4; ++nn) o_sem[(g * 4 + nn) * 57 + c] = v[nn] + bs[c];
        } else if (c < 67) {
#pragma unroll
            for (int nn = 0; nn < 4; ++nn) o_semins[(g * 4 + nn) * 10 + (c - 57)] = v[nn] + bsi[c - 57];
        } else if (c == 67) {
#pragma unroll
            for (int nn = 0; nn < 4; ++nn) {
                const float e = v[nn] + be[0];
                o_exists[g * 4 + nn] = e;
                ok[g * 4 + nn] = (e > 0.f) ? 1 : 0;
            }
        }
    } else {
        const float gwc = gw[c], gbc = gb[c], bgcc = bgc[c];
#pragma unroll
        for (int nn = 0; nn < 4; ++nn) {
            const float g0 = v[nn] + bgcc;
            float s = g0;
            s += __shfl_xor(s, 1); s += __shfl_xor(s, 2); s += __shfl_xor(s, 4);
            const float m = s * 0.125f;
            const float d = g0 - m;
            float q2 = d * d;
            q2 += __shfl_xor(q2, 1); q2 += __shfl_xor(q2, 2); q2 += __shfl_xor(q2, 4);
            const float var = q2 * 0.125f;
            o_geo[(g * 4 + nn) * 256 + c] = lrelu(d / sqrtf(var + 1e-5f) * gwc + gbc);
        }
    }
}

// ---------------- edge_k: el = lrelu(P_i+Q_j+bel), logits (unchanged) --------
__global__ __launch_bounds__(256) void edge_k(
    const float* __restrict__ P, const float* __restrict__ Q,
    const float* __restrict__ bel, const float* __restrict__ Wee,
    const float* __restrict__ bee,
    u16* __restrict__ el, float* __restrict__ o_edge) {
    const int pair = blockIdx.x * 4 + (threadIdx.x >> 6);
    const int l = threadIdx.x & 63;
    const int i = pair >> 7, j = pair & 127;
    f32x4 p = *(const f32x4*)(P + i * 256 + l * 4);
    f32x4 q = *(const f32x4*)(Q + j * 256 + l * 4);
    f32x4 b = *(const f32x4*)(bel + l * 4);
    float e0 = lrelu(p[0] + q[0] + b[0]);
    float e1 = lrelu(p[1] + q[1] + b[1]);
    float e2 = lrelu(p[2] + q[2] + b[2]);
    float e3 = lrelu(p[3] + q[3] + b[3]);
    ushort4 st; st.x = f2bf(e0); st.y = f2bf(e1); st.z = f2bf(e2); st.w = f2bf(e3);
    *(ushort4*)(el + (size_t)pair * 256 + l * 4) = st;
    f32x4 w;
    w = *(const f32x4*)(Wee + 0 * 256 + l * 4);
    float a0 = e0 * w[0] + e1 * w[1] + e2 * w[2] + e3 * w[3];
    w = *(const f32x4*)(Wee + 1 * 256 + l * 4);
    float a1 = e0 * w[0] + e1 * w[1] + e2 * w[2] + e3 * w[3];
    w = *(const f32x4*)(Wee + 2 * 256 + l * 4);
    float a2 = e0 * w[0] + e1 * w[1] + e2 * w[2] + e3 * w[3];
    w = *(const f32x4*)(Wee + 3 * 256 + l * 4);
    float a3 = e0 * w[0] + e1 * w[1] + e2 * w[2] + e3 * w[3];
#pragma unroll
    for (int mk = 1; mk < 64; mk <<= 1) {
        a0 += __shfl_xor(a0, mk); a1 += __shfl_xor(a1, mk);
        a2 += __shfl_xor(a2, mk); a3 += __shfl_xor(a3, mk);
    }
    if (l == 0) {
        f32x4 o;
        o[0] = a0 + bee[0]; o[1] = a1 + bee[1];
        o[2] = a2 + bee[2]; o[3] = a3 + bee[3];
        *(f32x4*)(o_edge + (size_t)pair * 4) = o;
    }
}

// ---------------- node_gemv: An1/Bn1 from x1 (split-K) -----------------------
__global__ __launch_bounds__(256) void node_gemv(
    const float* __restrict__ cat, const float* __restrict__ WT_n,
    float* __restrict__ An, float* __restrict__ Bn) {
    const int ct = blockIdx.x & 1, g = blockIdx.x >> 1;
    const int tid = threadIdx.x, lane = tid & 63, w = tid >> 6;
    __shared__ float xs[4][256];
    __shared__ float part[4][4][256];
    for (int idx = tid; idx < 1024; idx += 256) {
        const int nn = idx >> 8, k = idx & 255;
        xs[nn][k] = cat[(g * 4 + nn) * 768 + 256 + k];
    }
    __syncthreads();
    f32x4 a0{0,0,0,0}, a1{0,0,0,0}, a2{0,0,0,0}, a3{0,0,0,0};
    const float* wp = WT_n + (size_t)(w * 64) * 512 + ct * 256 + lane * 4;
#pragma unroll 4
    for (int kk = 0; kk < 64; ++kk) {
        const int k = w * 64 + kk;
        f32x4 wv = *(const f32x4*)wp; wp += 512;
        a0 += wv * xs[0][k];
        a1 += wv * xs[1][k];
        a2 += wv * xs[2][k];
        a3 += wv * xs[3][k];
    }
    *(f32x4*)&part[w][0][lane * 4] = a0;
    *(f32x4*)&part[w][1][lane * 4] = a1;
    *(f32x4*)&part[w][2][lane * 4] = a2;
    *(f32x4*)&part[w][3][lane * 4] = a3;
    __syncthreads();
    const int c = tid;
    float* dst = ct ? Bn : An;
#pragma unroll
    for (int nn = 0; nn < 4; ++nn)
        dst[(g * 4 + nn) * 256 + c] = part[0][nn][c] + part[1][nn][c] + part[2][nn][c] + part[3][nn][c];
}

// ---------------- mp_k: 8-wave (j-halved) MFMA message passing ---------------
__global__ __launch_bounds__(512) void mp_k(
    const u16* __restrict__ el, const float* __restrict__ An,
    const float* __restrict__ Bn, const float* __restrict__ Wne_it,
    const float* __restrict__ bne_it, const u16* __restrict__ W3p_it,
    const float* __restrict__ logits,
    const int* __restrict__ ok, float* __restrict__ xout /* stride 768 */) {
    const int i = blockIdx.x;
    const int tid = threadIdx.x;
    if (!ok[i]) { if (tid < 256) xout[i * 768 + tid] = 0.f; return; }
    const int l = tid & 63, wid = tid >> 6;
    const int jh = wid >> 2, hq = wid & 3;
    const int lr = l & 15, lq = l >> 4;
    const int h0 = hq * 64;
    __shared__ float red[2][4][4][16];

    bf16x8 bfr[4][8];
    float an[4], bnev[4];
    f32x4 w4[4];
#pragma unroll
    for (int nt = 0; nt < 4; ++nt) {
#pragma unroll
        for (int ks = 0; ks < 8; ++ks) {
            U8 u;
            u.q = ((const uint4*)W3p_it)[(hq * 4 + nt) * 512 + ks * 64 + l];
            bfr[nt][ks] = u.v;
        }
        const int h = h0 + nt * 16 + lr;
        an[nt] = An[i * 256 + h];
        bnev[nt] = bne_it[h];
        w4[nt] = *(const f32x4*)(Wne_it + (size_t)h * 772 + 768);
    }
    unsigned long long bl1 = __ballot(ok[l] != 0);
    unsigned long long bl2 = __ballot(ok[64 + l] != 0);
    unsigned actmask = 0;
#pragma unroll
    for (int jc = 0; jc < 4; ++jc) {
        if ((bl1 >> (jc * 16)) & 0xFFFFull) actmask |= (1u << jc);
        if ((bl2 >> (jc * 16)) & 0xFFFFull) actmask |= (1u << (4 + jc));
    }
    float rm0 = -1e30f, rm1 = -1e30f, rm2 = -1e30f, rm3 = -1e30f;
    for (int jc = jh * 4; jc < jh * 4 + 4; ++jc) {
        if (!(actmask & (1u << jc))) continue;
        f32x4 acc0{0.f,0.f,0.f,0.f}, acc1{0.f,0.f,0.f,0.f};
        f32x4 acc2{0.f,0.f,0.f,0.f}, acc3{0.f,0.f,0.f,0.f};
#pragma unroll
        for (int ks = 0; ks < 8; ++ks) {
            U8 u;
            u.q = *(const uint4*)(el + (size_t)(i * 128 + jc * 16 + lr) * 256 + ks * 32 + lq * 8);
            bf16x8 af = u.v;
            acc0 = mfma_(af, bfr[0][ks], acc0);
            acc1 = mfma_(af, bfr[1][ks], acc1);
            acc2 = mfma_(af, bfr[2][ks], acc2);
            acc3 = mfma_(af, bfr[3][ks], acc3);
        }
#pragma unroll
        for (int r = 0; r < 4; ++r) {
            const int j = jc * 16 + lq * 4 + r;
            if (!ok[j]) continue;
            f32x4 lg = *(const f32x4*)(logits + (size_t)(i * 128 + j) * 4);
            bool any = (lg[0] > 0.f) | (lg[1] > 0.f) | (lg[2] > 0.f) | (lg[3] > 0.f);
            if (!any) continue;
            float b0 = Bn[j * 256 + h0 + 0 * 16 + lr];
            float b1 = Bn[j * 256 + h0 + 1 * 16 + lr];
            float b2 = Bn[j * 256 + h0 + 2 * 16 + lr];
            float b3 = Bn[j * 256 + h0 + 3 * 16 + lr];
            float amx0 = -1e30f, amx1 = -1e30f, amx2 = -1e30f, amx3 = -1e30f;
#pragma unroll
            for (int t = 0; t < 4; ++t) {
                if (lg[t] > 0.f) {
                    amx0 = fmaxf(amx0, w4[0][t] * lg[t]);
                    amx1 = fmaxf(amx1, w4[1][t] * lg[t]);
                    amx2 = fmaxf(amx2, w4[2][t] * lg[t]);
                    amx3 = fmaxf(amx3, w4[3][t] * lg[t]);
                }
            }
            rm0 = fmaxf(rm0, lrelu(acc0[r] + an[0] + b0 + bnev[0] + amx0));
            rm1 = fmaxf(rm1, lrelu(acc1[r] + an[1] + b1 + bnev[1] + amx1));
            rm2 = fmaxf(rm2, lrelu(acc2[r] + an[2] + b2 + bnev[2] + amx2));
            rm3 = fmaxf(rm3, lrelu(acc3[r] + an[3] + b3 + bnev[3] + amx3));
        }
    }
    rm0 = fmaxf(rm0, __shfl_xor(rm0, 16)); rm0 = fmaxf(rm0, __shfl_xor(rm0, 32));
    rm1 = fmaxf(rm1, __shfl_xor(rm1, 16)); rm1 = fmaxf(rm1, __shfl_xor(rm1, 32));
    rm2 = fmaxf(rm2, __shfl_xor(rm2, 16)); rm2 = fmaxf(rm2, __shfl_xor(rm2, 32));
    rm3 = fmaxf(rm3, __shfl_xor(rm3, 16)); rm3 = fmaxf(rm3, __shfl_xor(rm3, 32));
    if (lq == 0) {
        red[jh][hq][0][lr] = rm0;
        red[jh][hq][1][lr] = rm1;
        red[jh][hq][2][lr] = rm2;
        red[jh][hq][3][lr] = rm3;
    }
    __syncthreads();
    if (jh == 0 && lq == 0) {
#pragma unroll
        for (int nt = 0; nt < 4; ++nt) {
            float f = fmaxf(red[0][hq][nt][lr], red[1][hq][nt][lr]);
            xout[i * 768 + h0 + nt * 16 + lr] = fmaxf(f, 0.f);
        }
    }
}

// ---------------- head_gemv: fused 2-layer head, split-K ---------------------
__global__ __launch_bounds__(256) void head_gemv(
    const float* __restrict__ cat, const float* __restrict__ WT_c,
    const float* __restrict__ bc, const float* __restrict__ WT_c2,
    const float* __restrict__ bc2, float* __restrict__ o_child) {
    const int i = blockIdx.x;
    const int tid = threadIdx.x, lane = tid & 63, w = tid >> 6;
    __shared__ float xs[768];
    __shared__ float part[4][256];
    __shared__ float ch[256];
    for (int idx = tid; idx < 768; idx += 256) xs[idx] = cat[i * 768 + idx];
    __syncthreads();
    f32x4 acc{0,0,0,0};
    const float* wp = WT_c + (size_t)(w * 192) * 256 + lane * 4;
#pragma unroll 4
    for (int kk = 0; kk < 192; ++kk) {
        f32x4 wv = *(const f32x4*)wp; wp += 256;
        acc += wv * xs[w * 192 + kk];
    }
    *(f32x4*)&part[w][lane * 4] = acc;
    __syncthreads();
    ch[tid] = lrelu(part[0][tid] + part[1][tid] + part[2][tid] + part[3][tid] + bc[tid]);
    __syncthreads();
    f32x4 acc2{0,0,0,0};
    wp = WT_c2 + (size_t)(w * 64) * 256 + lane * 4;
#pragma unroll 4
    for (int kk = 0; kk < 64; ++kk) {
        f32x4 wv = *(const f32x4*)wp; wp += 256;
        acc2 += wv * ch[w * 64 + kk];
    }
    __syncthreads();
    *(f32x4*)&part[w][lane * 4] = acc2;
    __syncthreads();
    o_child[i * 256 + tid] = lrelu(part[0][tid] + part[1][tid] + part[2][tid] + part[3][tid] + bc2[tid]);
}

extern "C" void kernel_launch(void* const* d_in, const int* in_sizes, int n_in,
                              void* d_out, int out_size, void* d_ws, size_t ws_size,
                              hipStream_t stream) {
    (void)in_sizes; (void)n_in; (void)out_size; (void)ws_size;
    const float* psf = (const float*)d_in[0];
    const float* pgf = (const float*)d_in[1];
    const float* Wp  = (const float*)d_in[2];
    const float* bp  = (const float*)d_in[3];
    const float* We  = (const float*)d_in[4];
    const float* be  = (const float*)d_in[5];
    const float* Ws  = (const float*)d_in[6];
    const float* bs  = (const float*)d_in[7];
    const float* Wsi = (const float*)d_in[8];
    const float* bsi = (const float*)d_in[9];
    const float* Wel = (const float*)d_in[10];
    const float* bel = (const float*)d_in[11];
    const float* Wee = (const float*)d_in[12];
    const float* bee = (const float*)d_in[13];
    const float* Wne = (const float*)d_in[14];
    const float* bne = (const float*)d_in[15];
    const float* Wc  = (const float*)d_in[16];
    const float* bc  = (const float*)d_in[17];
    const float* Wc2 = (const float*)d_in[18];
    const float* bc2 = (const float*)d_in[19];
    const float* Wgc = (const float*)d_in[20];
    const float* bgc = (const float*)d_in[21];
    const float* Wgp = (const float*)d_in[22];
    const float* bgp = (const float*)d_in[23];
    const float* gw  = (const float*)d_in[24];
    const float* gb  = (const float*)d_in[25];

    float* ws   = (float*)d_ws;
    float* pg   = ws;                    // 32768
    float* cat  = ws + 32768;            // 98304 (128 x 768: x0|x1|x2)
    float* P    = ws + 131072;           // 32768
    float* Q    = ws + 163840;           // 32768
    float* An   = ws + 196608;           // 32768
    float* Bn   = ws + 229376;           // 32768
    int*   ok   = (int*)(ws + 262144);   // 128
    u16*   el   = (u16*)(ws + 262272);   // 16384x256 bf16 = 2097152 words
    u16*   W3p  = (u16*)(ws + 2359424);  // 2 x 65536 u16 = 65536 words
    float* WT_a = ws + 2424960;          // 256 x 1280
    float* WT_g = ws + 2752640;          // 256 x 256
    float* WT_n = ws + 2818176;          // 256 x 512
    float* WT_c = ws + 2949248;          // 768 x 256
    float* WT_c2= ws + 3145856;          // 256 x 256  (total 12.25 MiB)

    float* out = (float*)d_out;
    float* o_child  = out;
    float* o_geo    = out + 32768;
    float* o_sem    = out + 65536;
    float* o_semins = out + 72832;
    float* o_exists = out + 74112;
    float* o_edge   = out + 74240;

    pack_all<<<256, 256, 0, stream>>>(Wel, Wne, Ws, Wsi, We, Wgc, Wc, Wc2,
                                      WT_a, WT_g, WT_n, WT_c, WT_c2, W3p);
    big_matvec<<<2048, 256, 0, stream>>>(Wp, bp, Wgp, bgp, psf, pgf, cat, pg);
    stage1_gemv<<<192, 256, 0, stream>>>(cat, pg, WT_a, WT_g, bgc, gw, gb,
                                         be, bs, bsi, P, Q, An, Bn, ok,
                                         o_geo, o_sem, o_semins, o_exists);
    edge_k<<<4096, 256, 0, stream>>>(P, Q, bel, Wee, bee, el, o_edge);
    mp_k<<<128, 512, 0, stream>>>(el, An, Bn, Wne, bne, W3p,
                                  o_edge, ok, cat + 256);
    node_gemv<<<64, 256, 0, stream>>>(cat, WT_n, An, Bn);
    mp_k<<<128, 512, 0, stream>>>(el, An, Bn, Wne + 256 * 772, bne + 256,
                                  W3p + 65536, o_edge, ok, cat + 512);
    head_gemv<<<128, 256, 0, stream>>>(cat, WT_c, bc, WT_c2, bc2, o_child);
}

// Round 7
// 234.303 us; speedup vs baseline: 1.4520x; 1.0313x over previous
//
#include <hip/hip_runtime.h>

typedef unsigned short u16;
typedef __bf16 bf16x8 __attribute__((ext_vector_type(8)));
typedef float f32x4 __attribute__((ext_vector_type(4)));

union U8 { ushort4 h4[2]; uint4 q; bf16x8 v; };

__device__ __forceinline__ u16 f2bf(float f) {
    union { float f; unsigned int u; } v; v.f = f;
    unsigned int u = v.u;
    unsigned int r = (u + 0x7FFFu + ((u >> 16) & 1u)) >> 16;
    return (u16)r;
}
__device__ __forceinline__ float lrelu(float x) { return x > 0.f ? x : 0.01f * x; }

__device__ __forceinline__ f32x4 mfma_(bf16x8 a, bf16x8 b, f32x4 c) {
    return __builtin_amdgcn_mfma_f32_16x16x32_bf16(a, b, c, 0, 0, 0);
}

// ---------------- pack_all: W^T transposes + W3 MFMA-frag pack + W4 pack -----
// blocks: [0,80) WT_a | [80,96) WT_g | [96,128) WT_n | [128,176) WT_c |
//         [176,192) WT_c2 | [192,256) W3p | [256,258) W4p
__global__ __launch_bounds__(256) void pack_all(
    const float* __restrict__ Wel, const float* __restrict__ Wne,
    const float* __restrict__ Ws, const float* __restrict__ Wsi,
    const float* __restrict__ We, const float* __restrict__ Wgc,
    const float* __restrict__ Wc, const float* __restrict__ Wc2,
    float* __restrict__ WT_a, float* __restrict__ WT_g,
    float* __restrict__ WT_n, float* __restrict__ WT_c,
    float* __restrict__ WT_c2, u16* __restrict__ W3p,
    float* __restrict__ W4p) {
    const int b = blockIdx.x, tid = threadIdx.x;
    if (b >= 256) {   // W4 pack: Wne[it][h][768..772) -> W4p[it*1024 + h*4 + t]
        const int it = b - 256;
        for (int idx = tid; idx < 1024; idx += 256) {
            W4p[it * 1024 + idx] =
                Wne[(size_t)it * 197632 + (size_t)(idx >> 2) * 772 + 768 + (idx & 3)];
        }
        return;
    }
    if (b >= 192) {  // W3 fragment pack (validated rounds 3-6)
        const int tg = (b - 192) * 256 + tid;   // 0..16383
        const int it = tg >> 13;
        const int r = tg & 8191;
        const int wid = r >> 11, nt = (r >> 9) & 3, ks = (r >> 6) & 7, l = r & 63;
        const int lr = l & 15, lq = l >> 4;
        const int h = wid * 64 + nt * 16 + lr;
        const int k0 = ks * 32 + lq * 8;
        const float* src = Wne + (size_t)it * 197632 + (size_t)h * 772 + 512 + k0;
        f32x4 a = *(const f32x4*)src;
        f32x4 c = *(const f32x4*)(src + 4);
        U8 u;
        u.h4[0].x = f2bf(a[0]); u.h4[0].y = f2bf(a[1]);
        u.h4[0].z = f2bf(a[2]); u.h4[0].w = f2bf(a[3]);
        u.h4[1].x = f2bf(c[0]); u.h4[1].y = f2bf(c[1]);
        u.h4[1].z = f2bf(c[2]); u.h4[1].w = f2bf(c[3]);
        ((uint4*)W3p)[tg] = u.q;
        return;
    }
    __shared__ float lds[64][65];
    const int lane = tid & 63, sub = tid >> 6;
    int src_id, ct, kt; float* dst; int ldd;
    if (b < 80)       { src_id = 0; ct = b >> 2;        kt = b & 3;        dst = WT_a;  ldd = 1280; }
    else if (b < 96)  { src_id = 1; ct = (b - 80) >> 2; kt = (b - 80) & 3; dst = WT_g;  ldd = 256; }
    else if (b < 128) { src_id = 2; ct = (b - 96) >> 2; kt = (b - 96) & 3; dst = WT_n;  ldd = 512; }
    else if (b < 176) { src_id = 3; ct = (b - 128) / 12; kt = (b - 128) % 12; dst = WT_c; ldd = 256; }
    else              { src_id = 4; ct = (b - 176) >> 2; kt = (b - 176) & 3; dst = WT_c2; ldd = 256; }
    const int c0 = ct * 64, k0 = kt * 64;
#pragma unroll 4
    for (int p = 0; p < 16; ++p) {
        const int row = p * 4 + sub;
        const int cabs = c0 + row;
        const float* base = nullptr;
        if (src_id == 0) {
            if (cabs < 256)       base = Wel + (size_t)cabs * 512;
            else if (cabs < 512)  base = Wel + (size_t)(cabs - 256) * 512 + 256;
            else if (cabs < 768)  base = Wne + (size_t)(cabs - 512) * 772;
            else if (cabs < 1024) base = Wne + (size_t)(cabs - 768) * 772 + 256;
            else if (cabs < 1081) base = Ws + (size_t)(cabs - 1024) * 256;
            else if (cabs < 1091) base = Wsi + (size_t)(cabs - 1081) * 256;
            else if (cabs == 1091) base = We;
        } else if (src_id == 1) {
            base = Wgc + (size_t)cabs * 256;
        } else if (src_id == 2) {
            base = (cabs < 256) ? Wne + 197632 + (size_t)cabs * 772
                                : Wne + 197632 + (size_t)(cabs - 256) * 772 + 256;
        } else if (src_id == 3) {
            base = Wc + (size_t)cabs * 768;
        } else {
            base = Wc2 + (size_t)cabs * 256;
        }
        lds[row][lane] = base ? base[k0 + lane] : 0.f;
    }
    __syncthreads();
#pragma unroll 4
    for (int p = 0; p < 16; ++p) {
        const int kr = p * 4 + sub;
        dst[(size_t)(k0 + kr) * ldd + c0 + lane] = lds[lane][kr];
    }
}

// ---------------- big_matvec: 4 rows/wave, interleaved reduce chains ---------
__global__ __launch_bounds__(256) void big_matvec(
    const float* __restrict__ Wp, const float* __restrict__ bp,
    const float* __restrict__ Wgp, const float* __restrict__ bgp,
    const float* __restrict__ psf, const float* __restrict__ pgf,
    float* __restrict__ cat, float* __restrict__ pg) {
    const int wg = blockIdx.x * 4 + (threadIdx.x >> 6);  // 0..8191
    const int l = threadIdx.x & 63;
    f32x4 xa = *(const f32x4*)(psf + l * 4);
    f32x4 xg = *(const f32x4*)(pgf + l * 4);
    {
        const int r0 = wg * 4;
        f32x4 w0 = *(const f32x4*)(Wp + (size_t)r0 * 256 + l * 4);
        f32x4 w1 = *(const f32x4*)(Wp + (size_t)(r0 + 1) * 256 + l * 4);
        f32x4 w2 = *(const f32x4*)(Wp + (size_t)(r0 + 2) * 256 + l * 4);
        f32x4 w3 = *(const f32x4*)(Wp + (size_t)(r0 + 3) * 256 + l * 4);
        float s0 = w0[0]*xa[0] + w0[1]*xa[1] + w0[2]*xa[2] + w0[3]*xa[3];
        float s1 = w1[0]*xa[0] + w1[1]*xa[1] + w1[2]*xa[2] + w1[3]*xa[3];
        float s2 = w2[0]*xa[0] + w2[1]*xa[1] + w2[2]*xa[2] + w2[3]*xa[3];
        float s3 = w3[0]*xa[0] + w3[1]*xa[1] + w3[2]*xa[2] + w3[3]*xa[3];
#pragma unroll
        for (int m = 1; m < 64; m <<= 1) {
            s0 += __shfl_xor(s0, m); s1 += __shfl_xor(s1, m);
            s2 += __shfl_xor(s2, m); s3 += __shfl_xor(s3, m);
        }
        if (l == 0) {
            f32x4 bv = *(const f32x4*)(bp + r0);
            f32x4 o; o[0] = lrelu(s0 + bv[0]); o[1] = lrelu(s1 + bv[1]);
            o[2] = lrelu(s2 + bv[2]); o[3] = lrelu(s3 + bv[3]);
            *(f32x4*)(cat + (r0 >> 8) * 768 + (r0 & 255)) = o;
        }
    }
    {
        const int r0 = wg * 4;
        f32x4 w0 = *(const f32x4*)(Wgp + (size_t)r0 * 256 + l * 4);
        f32x4 w1 = *(const f32x4*)(Wgp + (size_t)(r0 + 1) * 256 + l * 4);
        f32x4 w2 = *(const f32x4*)(Wgp + (size_t)(r0 + 2) * 256 + l * 4);
        f32x4 w3 = *(const f32x4*)(Wgp + (size_t)(r0 + 3) * 256 + l * 4);
        float s0 = w0[0]*xg[0] + w0[1]*xg[1] + w0[2]*xg[2] + w0[3]*xg[3];
        float s1 = w1[0]*xg[0] + w1[1]*xg[1] + w1[2]*xg[2] + w1[3]*xg[3];
        float s2 = w2[0]*xg[0] + w2[1]*xg[1] + w2[2]*xg[2] + w2[3]*xg[3];
        float s3 = w3[0]*xg[0] + w3[1]*xg[1] + w3[2]*xg[2] + w3[3]*xg[3];
#pragma unroll
        for (int m = 1; m < 64; m <<= 1) {
            s0 += __shfl_xor(s0, m); s1 += __shfl_xor(s1, m);
            s2 += __shfl_xor(s2, m); s3 += __shfl_xor(s3, m);
        }
        if (l == 0) {
            f32x4 bv = *(const f32x4*)(bgp + r0);
            f32x4 o; o[0] = lrelu(s0 + bv[0]); o[1] = lrelu(s1 + bv[1]);
            o[2] = lrelu(s2 + bv[2]); o[3] = lrelu(s3 + bv[3]);
            *(f32x4*)(pg + r0) = o;
        }
    }
}

// ---------------- stage1_gemv: split-K register GEMV, 4 nodes/block ----------
__global__ __launch_bounds__(256) void stage1_gemv(
    const float* __restrict__ cat, const float* __restrict__ pgin,
    const float* __restrict__ WT_a, const float* __restrict__ WT_g,
    const float* __restrict__ bgc, const float* __restrict__ gw,
    const float* __restrict__ gb, const float* __restrict__ be,
    const float* __restrict__ bs, const float* __restrict__ bsi,
    float* __restrict__ P, float* __restrict__ Q,
    float* __restrict__ An, float* __restrict__ Bn, int* __restrict__ ok,
    float* __restrict__ o_geo, float* __restrict__ o_sem,
    float* __restrict__ o_semins, float* __restrict__ o_exists) {
    const int ct = blockIdx.x % 6, g = blockIdx.x / 6;
    const int tid = threadIdx.x, lane = tid & 63, w = tid >> 6;
    __shared__ float xs[4][256];
    __shared__ float part[4][4][256];
    const float* WT; int ldw, c0;
    if (ct == 5) { WT = WT_g; ldw = 256; c0 = 0; }
    else         { WT = WT_a; ldw = 1280; c0 = ct * 256; }
    for (int idx = tid; idx < 1024; idx += 256) {
        const int nn = idx >> 8, k = idx & 255;
        xs[nn][k] = (ct == 5) ? pgin[(g * 4 + nn) * 256 + k]
                              : cat[(g * 4 + nn) * 768 + k];
    }
    __syncthreads();
    f32x4 a0{0,0,0,0}, a1{0,0,0,0}, a2{0,0,0,0}, a3{0,0,0,0};
    const float* wp = WT + (size_t)(w * 64) * ldw + c0 + lane * 4;
#pragma unroll 4
    for (int kk = 0; kk < 64; ++kk) {
        const int k = w * 64 + kk;
        f32x4 wv = *(const f32x4*)wp; wp += ldw;
        a0 += wv * xs[0][k];
        a1 += wv * xs[1][k];
        a2 += wv * xs[2][k];
        a3 += wv * xs[3][k];
    }
    *(f32x4*)&part[w][0][lane * 4] = a0;
    *(f32x4*)&part[w][1][lane * 4] = a1;
    *(f32x4*)&part[w][2][lane * 4] = a2;
    *(f32x4*)&part[w][3][lane * 4] = a3;
    __syncthreads();
    const int c = tid;
    float v[4];
#pragma unroll
    for (int nn = 0; nn < 4; ++nn)
        v[nn] = part[0][nn][c] + part[1][nn][c] + part[2][nn][c] + part[3][nn][c];
    if (ct < 4) {
        float* dst = (ct == 0) ? P : (ct == 1) ? Q : (ct == 2) ? An : Bn;
#pragma unroll
        for (int nn = 0; nn < 4; ++nn) dst[(g * 4 + nn) * 256 + c] = v[nn];
    } else if (ct == 4) {
        if (c < 57) {
#pragma unroll
            for (int nn = 0; nn < 4; ++nn) o_sem[(g * 4 + nn) * 57 + c] = v[nn] + bs[c];
        } else if (c < 67) {
#pragma unroll
            for (int nn = 0; nn < 4; ++nn) o_semins[(g * 4 + nn) * 10 + (c - 57)] = v[nn] + bsi[c - 57];
        } else if (c == 67) {
#pragma unroll
            for (int nn = 0; nn < 4; ++nn) {
                const float e = v[nn] + be[0];
                o_exists[g * 4 + nn] = e;
                ok[g * 4 + nn] = (e > 0.f) ? 1 : 0;
            }
        }
    } else {
        const float gwc = gw[c], gbc = gb[c], bgcc = bgc[c];
#pragma unroll
        for (int nn = 0; nn < 4; ++nn) {
            const float g0 = v[nn] + bgcc;
            float s = g0;
            s += __shfl_xor(s, 1); s += __shfl_xor(s, 2); s += __shfl_xor(s, 4);
            const float m = s * 0.125f;
            const float d = g0 - m;
            float q2 = d * d;
            q2 += __shfl_xor(q2, 1); q2 += __shfl_xor(q2, 2); q2 += __shfl_xor(q2, 4);
            const float var = q2 * 0.125f;
            o_geo[(g * 4 + nn) * 256 + c] = lrelu(d / sqrtf(var + 1e-5f) * gwc + gbc);
        }
    }
}

// ---------------- edge_k: el = lrelu(P_i+Q_j+bel), logits --------------------
__global__ __launch_bounds__(256) void edge_k(
    const float* __restrict__ P, const float* __restrict__ Q,
    const float* __restrict__ bel, const float* __restrict__ Wee,
    const float* __restrict__ bee,
    u16* __restrict__ el, float* __restrict__ o_edge) {
    const int pair = blockIdx.x * 4 + (threadIdx.x >> 6);
    const int l = threadIdx.x & 63;
    const int i = pair >> 7, j = pair & 127;
    f32x4 p = *(const f32x4*)(P + i * 256 + l * 4);
    f32x4 q = *(const f32x4*)(Q + j * 256 + l * 4);
    f32x4 b = *(const f32x4*)(bel + l * 4);
    float e0 = lrelu(p[0] + q[0] + b[0]);
    float e1 = lrelu(p[1] + q[1] + b[1]);
    float e2 = lrelu(p[2] + q[2] + b[2]);
    float e3 = lrelu(p[3] + q[3] + b[3]);
    ushort4 st; st.x = f2bf(e0); st.y = f2bf(e1); st.z = f2bf(e2); st.w = f2bf(e3);
    *(ushort4*)(el + (size_t)pair * 256 + l * 4) = st;
    f32x4 w;
    w = *(const f32x4*)(Wee + 0 * 256 + l * 4);
    float a0 = e0 * w[0] + e1 * w[1] + e2 * w[2] + e3 * w[3];
    w = *(const f32x4*)(Wee + 1 * 256 + l * 4);
    float a1 = e0 * w[0] + e1 * w[1] + e2 * w[2] + e3 * w[3];
    w = *(const f32x4*)(Wee + 2 * 256 + l * 4);
    float a2 = e0 * w[0] + e1 * w[1] + e2 * w[2] + e3 * w[3];
    w = *(const f32x4*)(Wee + 3 * 256 + l * 4);
    float a3 = e0 * w[0] + e1 * w[1] + e2 * w[2] + e3 * w[3];
#pragma unroll
    for (int mk = 1; mk < 64; mk <<= 1) {
        a0 += __shfl_xor(a0, mk); a1 += __shfl_xor(a1, mk);
        a2 += __shfl_xor(a2, mk); a3 += __shfl_xor(a3, mk);
    }
    if (l == 0) {
        f32x4 o;
        o[0] = a0 + bee[0]; o[1] = a1 + bee[1];
        o[2] = a2 + bee[2]; o[3] = a3 + bee[3];
        *(f32x4*)(o_edge + (size_t)pair * 4) = o;
    }
}

// ---------------- mp_core: shared MFMA message-passing max-reduce ------------
// Produces xs[0..255] = x_next for node i (all 512 threads see it).
__device__ __forceinline__ void mp_core(
    const int i, const int tid,
    const u16* __restrict__ el, const float* __restrict__ Anp,
    const float* __restrict__ Bnp, const float* __restrict__ bne_it,
    const u16* __restrict__ W3p_it, const float* __restrict__ W4p_it,
    const float* __restrict__ logits, const int* __restrict__ ok,
    float* __restrict__ xs, float (*red)[4][4][16]) {
    const int l = tid & 63, wid = tid >> 6;
    const int jh = wid >> 2, hq = wid & 3;
    const int lr = l & 15, lq = l >> 4;
    const int h0 = hq * 64;
    bf16x8 bfr[4][8];
    float an[4], bnev[4];
    f32x4 w4[4];
#pragma unroll
    for (int nt = 0; nt < 4; ++nt) {
#pragma unroll
        for (int ks = 0; ks < 8; ++ks) {
            U8 u;
            u.q = ((const uint4*)W3p_it)[(hq * 4 + nt) * 512 + ks * 64 + l];
            bfr[nt][ks] = u.v;
        }
        const int h = h0 + nt * 16 + lr;
        an[nt] = Anp[i * 256 + h];
        bnev[nt] = bne_it[h];
        w4[nt] = *(const f32x4*)(W4p_it + h * 4);
    }
    unsigned long long bl1 = __ballot(ok[l] != 0);
    unsigned long long bl2 = __ballot(ok[64 + l] != 0);
    unsigned actmask = 0;
#pragma unroll
    for (int jc = 0; jc < 4; ++jc) {
        if ((bl1 >> (jc * 16)) & 0xFFFFull) actmask |= (1u << jc);
        if ((bl2 >> (jc * 16)) & 0xFFFFull) actmask |= (1u << (4 + jc));
    }
    float rm0 = -1e30f, rm1 = -1e30f, rm2 = -1e30f, rm3 = -1e30f;
    for (int jc = jh * 4; jc < jh * 4 + 4; ++jc) {
        if (!(actmask & (1u << jc))) continue;
        f32x4 acc0{0.f,0.f,0.f,0.f}, acc1{0.f,0.f,0.f,0.f};
        f32x4 acc2{0.f,0.f,0.f,0.f}, acc3{0.f,0.f,0.f,0.f};
#pragma unroll
        for (int ks = 0; ks < 8; ++ks) {
            U8 u;
            u.q = *(const uint4*)(el + (size_t)(i * 128 + jc * 16 + lr) * 256 + ks * 32 + lq * 8);
            bf16x8 af = u.v;
            acc0 = mfma_(af, bfr[0][ks], acc0);
            acc1 = mfma_(af, bfr[1][ks], acc1);
            acc2 = mfma_(af, bfr[2][ks], acc2);
            acc3 = mfma_(af, bfr[3][ks], acc3);
        }
#pragma unroll
        for (int r = 0; r < 4; ++r) {
            const int j = jc * 16 + lq * 4 + r;
            if (!ok[j]) continue;
            f32x4 lg = *(const f32x4*)(logits + (size_t)(i * 128 + j) * 4);
            bool any = (lg[0] > 0.f) | (lg[1] > 0.f) | (lg[2] > 0.f) | (lg[3] > 0.f);
            if (!any) continue;
            float b0 = Bnp[j * 256 + h0 + 0 * 16 + lr];
            float b1 = Bnp[j * 256 + h0 + 1 * 16 + lr];
            float b2 = Bnp[j * 256 + h0 + 2 * 16 + lr];
            float b3 = Bnp[j * 256 + h0 + 3 * 16 + lr];
            float amx0 = -1e30f, amx1 = -1e30f, amx2 = -1e30f, amx3 = -1e30f;
#pragma unroll
            for (int t = 0; t < 4; ++t) {
                if (lg[t] > 0.f) {
                    amx0 = fmaxf(amx0, w4[0][t] * lg[t]);
                    amx1 = fmaxf(amx1, w4[1][t] * lg[t]);
                    amx2 = fmaxf(amx2, w4[2][t] * lg[t]);
                    amx3 = fmaxf(amx3, w4[3][t] * lg[t]);
                }
            }
            rm0 = fmaxf(rm0, lrelu(acc0[r] + an[0] + b0 + bnev[0] + amx0));
            rm1 = fmaxf(rm1, lrelu(acc1[r] + an[1] + b1 + bnev[1] + amx1));
            rm2 = fmaxf(rm2, lrelu(acc2[r] + an[2] + b2 + bnev[2] + amx2));
            rm3 = fmaxf(rm3, lrelu(acc3[r] + an[3] + b3 + bnev[3] + amx3));
        }
    }
    rm0 = fmaxf(rm0, __shfl_xor(rm0, 16)); rm0 = fmaxf(rm0, __shfl_xor(rm0, 32));
    rm1 = fmaxf(rm1, __shfl_xor(rm1, 16)); rm1 = fmaxf(rm1, __shfl_xor(rm1, 32));
    rm2 = fmaxf(rm2, __shfl_xor(rm2, 16)); rm2 = fmaxf(rm2, __shfl_xor(rm2, 32));
    rm3 = fmaxf(rm3, __shfl_xor(rm3, 16)); rm3 = fmaxf(rm3, __shfl_xor(rm3, 32));
    if (lq == 0) {
        red[jh][hq][0][lr] = rm0;
        red[jh][hq][1][lr] = rm1;
        red[jh][hq][2][lr] = rm2;
        red[jh][hq][3][lr] = rm3;
    }
    __syncthreads();
    if (jh == 0 && lq == 0) {
#pragma unroll
        for (int nt = 0; nt < 4; ++nt) {
            float f = fmaxf(red[0][hq][nt][lr], red[1][hq][nt][lr]);
            xs[h0 + nt * 16 + lr] = fmaxf(f, 0.f);
        }
    }
    __syncthreads();
}

// ---------------- mp0_k: iteration 0 + fused node transform ------------------
__global__ __launch_bounds__(512) void mp0_k(
    const u16* __restrict__ el, const float* __restrict__ An,
    const float* __restrict__ Bn, const float* __restrict__ bne,
    const u16* __restrict__ W3p, const float* __restrict__ W4p,
    const float* __restrict__ logits, const int* __restrict__ ok,
    float* __restrict__ cat, const float* __restrict__ WT_n,
    float* __restrict__ An1, float* __restrict__ Bn1) {
    __shared__ float xs[256];
    __shared__ float red[2][4][4][16];
    const int i = blockIdx.x, tid = threadIdx.x;
    if (!ok[i]) {
        if (tid < 256) {
            cat[i * 768 + 256 + tid] = 0.f;
            An1[i * 256 + tid] = 0.f;
        } else {
            Bn1[i * 256 + (tid - 256)] = 0.f;
        }
        return;
    }
    mp_core(i, tid, el, An, Bn, bne, W3p, W4p, logits, ok, xs, red);
    if (tid < 256) cat[i * 768 + 256 + tid] = xs[tid];
    // fused node transform: An1/Bn1 = W1/W2 @ x1  (WT_n is [k][512], coalesced)
    float acc = 0.f;
    const float* wp = WT_n + tid;
#pragma unroll 8
    for (int k = 0; k < 256; ++k) acc += wp[(size_t)k * 512] * xs[k];
    if (tid < 256) An1[i * 256 + tid] = acc;
    else Bn1[i * 256 + (tid - 256)] = acc;
}

// ---------------- mp1_k: iteration 1 + fused 2-layer head --------------------
__global__ __launch_bounds__(512) void mp1_k(
    const u16* __restrict__ el, const float* __restrict__ An1,
    const float* __restrict__ Bn1, const float* __restrict__ bne1,
    const u16* __restrict__ W3p1, const float* __restrict__ W4p1,
    const float* __restrict__ logits, const int* __restrict__ ok,
    const float* __restrict__ cat, const float* __restrict__ WT_c,
    const float* __restrict__ bc, const float* __restrict__ WT_c2,
    const float* __restrict__ bc2, float* __restrict__ o_child) {
    __shared__ float xs[256];
    __shared__ float red[2][4][4][16];
    __shared__ float cs[768];
    __shared__ float part[256];
    __shared__ float ch[256];
    const int i = blockIdx.x, tid = threadIdx.x;
    if (ok[i]) {
        mp_core(i, tid, el, An1, Bn1, bne1, W3p1, W4p1, logits, ok, xs, red);
    } else {
        if (tid < 256) xs[tid] = 0.f;
        __syncthreads();
    }
    // cs = [x0 | x1 | x2]:  x0,x1 from global, x2 from LDS (never hits HBM)
    cs[tid] = cat[i * 768 + tid];          // tid < 512 covers x0,x1
    if (tid < 256) cs[512 + tid] = xs[tid];
    __syncthreads();
    const int c = tid & 255, kh = tid >> 8;
    float acc = 0.f;
    {
        const float* wp = WT_c + (size_t)(kh * 384) * 256 + c;
        const float* xv = cs + kh * 384;
#pragma unroll 8
        for (int k = 0; k < 384; ++k) acc += wp[(size_t)k * 256] * xv[k];
    }
    if (kh == 1) part[c] = acc;
    __syncthreads();
    if (kh == 0) ch[c] = lrelu(acc + part[c] + bc[c]);
    __syncthreads();
    float acc2 = 0.f;
    {
        const float* wp = WT_c2 + (size_t)(kh * 128) * 256 + c;
        const float* xv = ch + kh * 128;
#pragma unroll 8
        for (int k = 0; k < 128; ++k) acc2 += wp[(size_t)k * 256] * xv[k];
    }
    if (kh == 1) part[c] = acc2;
    __syncthreads();
    if (kh == 0) o_child[i * 256 + c] = lrelu(acc2 + part[c] + bc2[c]);
}

extern "C" void kernel_launch(void* const* d_in, const int* in_sizes, int n_in,
                              void* d_out, int out_size, void* d_ws, size_t ws_size,
                              hipStream_t stream) {
    (void)in_sizes; (void)n_in; (void)out_size; (void)ws_size;
    const float* psf = (const float*)d_in[0];
    const float* pgf = (const float*)d_in[1];
    const float* Wp  = (const float*)d_in[2];
    const float* bp  = (const float*)d_in[3];
    const float* We  = (const float*)d_in[4];
    const float* be  = (const float*)d_in[5];
    const float* Ws  = (const float*)d_in[6];
    const float* bs  = (const float*)d_in[7];
    const float* Wsi = (const float*)d_in[8];
    const float* bsi = (const float*)d_in[9];
    const float* Wel = (const float*)d_in[10];
    const float* bel = (const float*)d_in[11];
    const float* Wee = (const float*)d_in[12];
    const float* bee = (const float*)d_in[13];
    const float* Wne = (const float*)d_in[14];
    const float* bne = (const float*)d_in[15];
    const float* Wc  = (const float*)d_in[16];
    const float* bc  = (const float*)d_in[17];
    const float* Wc2 = (const float*)d_in[18];
    const float* bc2 = (const float*)d_in[19];
    const float* Wgc = (const float*)d_in[20];
    const float* bgc = (const float*)d_in[21];
    const float* Wgp = (const float*)d_in[22];
    const float* bgp = (const float*)d_in[23];
    const float* gw  = (const float*)d_in[24];
    const float* gb  = (const float*)d_in[25];

    float* ws   = (float*)d_ws;
    float* pg   = ws;                    // 32768
    float* cat  = ws + 32768;            // 98304 (128 x 768: x0|x1|unused)
    float* P    = ws + 131072;           // 32768 (reused as An1 after edge_k)
    float* Q    = ws + 163840;           // 32768 (reused as Bn1 after edge_k)
    float* An   = ws + 196608;           // 32768
    float* Bn   = ws + 229376;           // 32768
    int*   ok   = (int*)(ws + 262144);   // 128
    u16*   el   = (u16*)(ws + 262272);   // 16384x256 bf16
    u16*   W3p  = (u16*)(ws + 2359424);  // 2 x 65536 u16
    float* WT_a = ws + 2424960;          // 256 x 1280
    float* WT_g = ws + 2752640;          // 256 x 256
    float* WT_n = ws + 2818176;          // 256 x 512
    float* WT_c = ws + 2949248;          // 768 x 256
    float* WT_c2= ws + 3145856;          // 256 x 256
    float* W4p  = ws + 3211392;          // 2 x 1024
    float* An1  = P;
    float* Bn1  = Q;

    float* out = (float*)d_out;
    float* o_child  = out;
    float* o_geo    = out + 32768;
    float* o_sem    = out + 65536;
    float* o_semins = out + 72832;
    float* o_exists = out + 74112;
    float* o_edge   = out + 74240;

    pack_all<<<258, 256, 0, stream>>>(Wel, Wne, Ws, Wsi, We, Wgc, Wc, Wc2,
                                      WT_a, WT_g, WT_n, WT_c, WT_c2, W3p, W4p);
    big_matvec<<<2048, 256, 0, stream>>>(Wp, bp, Wgp, bgp, psf, pgf, cat, pg);
    stage1_gemv<<<192, 256, 0, stream>>>(cat, pg, WT_a, WT_g, bgc, gw, gb,
                                         be, bs, bsi, P, Q, An, Bn, ok,
                                         o_geo, o_sem, o_semins, o_exists);
    edge_k<<<4096, 256, 0, stream>>>(P, Q, bel, Wee, bee, el, o_edge);
    mp0_k<<<128, 512, 0, stream>>>(el, An, Bn, bne, W3p, W4p,
                                   o_edge, ok, cat, WT_n, An1, Bn1);
    mp1_k<<<128, 512, 0, stream>>>(el, An1, Bn1, bne + 256, W3p + 65536,
                                   W4p + 1024, o_edge, ok, cat,
                                   WT_c, bc, WT_c2, bc2, o_child);
}

// Round 8
// 224.086 us; speedup vs baseline: 1.5182x; 1.0456x over previous
//
#include <hip/hip_runtime.h>

typedef unsigned short u16;
typedef __bf16 bf16x8 __attribute__((ext_vector_type(8)));
typedef float f32x4 __attribute__((ext_vector_type(4)));

union U8 { ushort4 h4[2]; uint4 q; bf16x8 v; };

__device__ __forceinline__ u16 f2bf(float f) {
    union { float f; unsigned int u; } v; v.f = f;
    unsigned int u = v.u;
    unsigned int r = (u + 0x7FFFu + ((u >> 16) & 1u)) >> 16;
    return (u16)r;
}
__device__ __forceinline__ float lrelu(float x) { return x > 0.f ? x : 0.01f * x; }

__device__ __forceinline__ f32x4 mfma_(bf16x8 a, bf16x8 b, f32x4 c) {
    return __builtin_amdgcn_mfma_f32_16x16x32_bf16(a, b, c, 0, 0, 0);
}

// ---------------- pack_all: W^T transposes + W3 MFMA-frag pack + W4 pack -----
// blocks: [0,80) WT_a | [80,96) WT_g | [96,128) WT_n | [128,176) WT_c |
//         [176,192) WT_c2 | [192,256) W3p | [256,258) W4p
__global__ __launch_bounds__(256) void pack_all(
    const float* __restrict__ Wel, const float* __restrict__ Wne,
    const float* __restrict__ Ws, const float* __restrict__ Wsi,
    const float* __restrict__ We, const float* __restrict__ Wgc,
    const float* __restrict__ Wc, const float* __restrict__ Wc2,
    float* __restrict__ WT_a, float* __restrict__ WT_g,
    float* __restrict__ WT_n, float* __restrict__ WT_c,
    float* __restrict__ WT_c2, u16* __restrict__ W3p,
    float* __restrict__ W4p) {
    const int b = blockIdx.x, tid = threadIdx.x;
    if (b >= 256) {   // W4 pack: Wne[it][h][768..772) -> W4p[it*1024 + h*4 + t]
        const int it = b - 256;
        for (int idx = tid; idx < 1024; idx += 256) {
            W4p[it * 1024 + idx] =
                Wne[(size_t)it * 197632 + (size_t)(idx >> 2) * 772 + 768 + (idx & 3)];
        }
        return;
    }
    if (b >= 192) {  // W3 fragment pack (validated rounds 3-7)
        const int tg = (b - 192) * 256 + tid;   // 0..16383
        const int it = tg >> 13;
        const int r = tg & 8191;
        const int wid = r >> 11, nt = (r >> 9) & 3, ks = (r >> 6) & 7, l = r & 63;
        const int lr = l & 15, lq = l >> 4;
        const int h = wid * 64 + nt * 16 + lr;
        const int k0 = ks * 32 + lq * 8;
        const float* src = Wne + (size_t)it * 197632 + (size_t)h * 772 + 512 + k0;
        f32x4 a = *(const f32x4*)src;
        f32x4 c = *(const f32x4*)(src + 4);
        U8 u;
        u.h4[0].x = f2bf(a[0]); u.h4[0].y = f2bf(a[1]);
        u.h4[0].z = f2bf(a[2]); u.h4[0].w = f2bf(a[3]);
        u.h4[1].x = f2bf(c[0]); u.h4[1].y = f2bf(c[1]);
        u.h4[1].z = f2bf(c[2]); u.h4[1].w = f2bf(c[3]);
        ((uint4*)W3p)[tg] = u.q;
        return;
    }
    __shared__ float lds[64][65];
    const int lane = tid & 63, sub = tid >> 6;
    int src_id, ct, kt; float* dst; int ldd;
    if (b < 80)       { src_id = 0; ct = b >> 2;        kt = b & 3;        dst = WT_a;  ldd = 1280; }
    else if (b < 96)  { src_id = 1; ct = (b - 80) >> 2; kt = (b - 80) & 3; dst = WT_g;  ldd = 256; }
    else if (b < 128) { src_id = 2; ct = (b - 96) >> 2; kt = (b - 96) & 3; dst = WT_n;  ldd = 512; }
    else if (b < 176) { src_id = 3; ct = (b - 128) / 12; kt = (b - 128) % 12; dst = WT_c; ldd = 256; }
    else              { src_id = 4; ct = (b - 176) >> 2; kt = (b - 176) & 3; dst = WT_c2; ldd = 256; }
    const int c0 = ct * 64, k0 = kt * 64;
#pragma unroll 4
    for (int p = 0; p < 16; ++p) {
        const int row = p * 4 + sub;
        const int cabs = c0 + row;
        const float* base = nullptr;
        if (src_id == 0) {
            if (cabs < 256)       base = Wel + (size_t)cabs * 512;
            else if (cabs < 512)  base = Wel + (size_t)(cabs - 256) * 512 + 256;
            else if (cabs < 768)  base = Wne + (size_t)(cabs - 512) * 772;
            else if (cabs < 1024) base = Wne + (size_t)(cabs - 768) * 772 + 256;
            else if (cabs < 1081) base = Ws + (size_t)(cabs - 1024) * 256;
            else if (cabs < 1091) base = Wsi + (size_t)(cabs - 1081) * 256;
            else if (cabs == 1091) base = We;
        } else if (src_id == 1) {
            base = Wgc + (size_t)cabs * 256;
        } else if (src_id == 2) {
            base = (cabs < 256) ? Wne + 197632 + (size_t)cabs * 772
                                : Wne + 197632 + (size_t)(cabs - 256) * 772 + 256;
        } else if (src_id == 3) {
            base = Wc + (size_t)cabs * 768;
        } else {
            base = Wc2 + (size_t)cabs * 256;
        }
        lds[row][lane] = base ? base[k0 + lane] : 0.f;
    }
    __syncthreads();
#pragma unroll 4
    for (int p = 0; p < 16; ++p) {
        const int kr = p * 4 + sub;
        dst[(size_t)(k0 + kr) * ldd + c0 + lane] = lds[lane][kr];
    }
}

// ---------------- big_matvec: 4 rows/wave, interleaved reduce chains ---------
__global__ __launch_bounds__(256) void big_matvec(
    const float* __restrict__ Wp, const float* __restrict__ bp,
    const float* __restrict__ Wgp, const float* __restrict__ bgp,
    const float* __restrict__ psf, const float* __restrict__ pgf,
    float* __restrict__ cat, float* __restrict__ pg) {
    const int wg = blockIdx.x * 4 + (threadIdx.x >> 6);  // 0..8191
    const int l = threadIdx.x & 63;
    f32x4 xa = *(const f32x4*)(psf + l * 4);
    f32x4 xg = *(const f32x4*)(pgf + l * 4);
    {
        const int r0 = wg * 4;
        f32x4 w0 = *(const f32x4*)(Wp + (size_t)r0 * 256 + l * 4);
        f32x4 w1 = *(const f32x4*)(Wp + (size_t)(r0 + 1) * 256 + l * 4);
        f32x4 w2 = *(const f32x4*)(Wp + (size_t)(r0 + 2) * 256 + l * 4);
        f32x4 w3 = *(const f32x4*)(Wp + (size_t)(r0 + 3) * 256 + l * 4);
        float s0 = w0[0]*xa[0] + w0[1]*xa[1] + w0[2]*xa[2] + w0[3]*xa[3];
        float s1 = w1[0]*xa[0] + w1[1]*xa[1] + w1[2]*xa[2] + w1[3]*xa[3];
        float s2 = w2[0]*xa[0] + w2[1]*xa[1] + w2[2]*xa[2] + w2[3]*xa[3];
        float s3 = w3[0]*xa[0] + w3[1]*xa[1] + w3[2]*xa[2] + w3[3]*xa[3];
#pragma unroll
        for (int m = 1; m < 64; m <<= 1) {
            s0 += __shfl_xor(s0, m); s1 += __shfl_xor(s1, m);
            s2 += __shfl_xor(s2, m); s3 += __shfl_xor(s3, m);
        }
        if (l == 0) {
            f32x4 bv = *(const f32x4*)(bp + r0);
            f32x4 o; o[0] = lrelu(s0 + bv[0]); o[1] = lrelu(s1 + bv[1]);
            o[2] = lrelu(s2 + bv[2]); o[3] = lrelu(s3 + bv[3]);
            *(f32x4*)(cat + (r0 >> 8) * 768 + (r0 & 255)) = o;
        }
    }
    {
        const int r0 = wg * 4;
        f32x4 w0 = *(const f32x4*)(Wgp + (size_t)r0 * 256 + l * 4);
        f32x4 w1 = *(const f32x4*)(Wgp + (size_t)(r0 + 1) * 256 + l * 4);
        f32x4 w2 = *(const f32x4*)(Wgp + (size_t)(r0 + 2) * 256 + l * 4);
        f32x4 w3 = *(const f32x4*)(Wgp + (size_t)(r0 + 3) * 256 + l * 4);
        float s0 = w0[0]*xg[0] + w0[1]*xg[1] + w0[2]*xg[2] + w0[3]*xg[3];
        float s1 = w1[0]*xg[0] + w1[1]*xg[1] + w1[2]*xg[2] + w1[3]*xg[3];
        float s2 = w2[0]*xg[0] + w2[1]*xg[1] + w2[2]*xg[2] + w2[3]*xg[3];
        float s3 = w3[0]*xg[0] + w3[1]*xg[1] + w3[2]*xg[2] + w3[3]*xg[3];
#pragma unroll
        for (int m = 1; m < 64; m <<= 1) {
            s0 += __shfl_xor(s0, m); s1 += __shfl_xor(s1, m);
            s2 += __shfl_xor(s2, m); s3 += __shfl_xor(s3, m);
        }
        if (l == 0) {
            f32x4 bv = *(const f32x4*)(bgp + r0);
            f32x4 o; o[0] = lrelu(s0 + bv[0]); o[1] = lrelu(s1 + bv[1]);
            o[2] = lrelu(s2 + bv[2]); o[3] = lrelu(s3 + bv[3]);
            *(f32x4*)(pg + r0) = o;
        }
    }
}

// ---------------- stage1_gemv: split-K register GEMV, 4 nodes/block ----------
// blockIdx = g*6 + ct;  ct 0:P(+zero x1/x2) 1:Q 2:An0 3:Bn0 4:heads 5:geo
__global__ __launch_bounds__(256) void stage1_gemv(
    const float* __restrict__ cat, float* __restrict__ cat_z,
    const float* __restrict__ pgin,
    const float* __restrict__ WT_a, const float* __restrict__ WT_g,
    const float* __restrict__ bgc, const float* __restrict__ gw,
    const float* __restrict__ gb, const float* __restrict__ be,
    const float* __restrict__ bs, const float* __restrict__ bsi,
    float* __restrict__ P, float* __restrict__ Q,
    float* __restrict__ An, float* __restrict__ Bn, int* __restrict__ ok,
    float* __restrict__ o_geo, float* __restrict__ o_sem,
    float* __restrict__ o_semins, float* __restrict__ o_exists) {
    const int ct = blockIdx.x % 6, g = blockIdx.x / 6;
    const int tid = threadIdx.x, lane = tid & 63, w = tid >> 6;
    __shared__ float xs[4][256];
    __shared__ float part[4][4][256];
    if (ct == 0) {  // zero-init x1/x2 slots for the atomicMax combine in mp_k
        for (int idx = tid; idx < 2048; idx += 256) {
            const int nn = idx >> 9, off = idx & 511;
            cat_z[(g * 4 + nn) * 768 + 256 + off] = 0.f;
        }
    }
    const float* WT; int ldw, c0;
    if (ct == 5) { WT = WT_g; ldw = 256; c0 = 0; }
    else         { WT = WT_a; ldw = 1280; c0 = ct * 256; }
    for (int idx = tid; idx < 1024; idx += 256) {
        const int nn = idx >> 8, k = idx & 255;
        xs[nn][k] = (ct == 5) ? pgin[(g * 4 + nn) * 256 + k]
                              : cat[(g * 4 + nn) * 768 + k];
    }
    __syncthreads();
    f32x4 a0{0,0,0,0}, a1{0,0,0,0}, a2{0,0,0,0}, a3{0,0,0,0};
    const float* wp = WT + (size_t)(w * 64) * ldw + c0 + lane * 4;
#pragma unroll 4
    for (int kk = 0; kk < 64; ++kk) {
        const int k = w * 64 + kk;
        f32x4 wv = *(const f32x4*)wp; wp += ldw;
        a0 += wv * xs[0][k];
        a1 += wv * xs[1][k];
        a2 += wv * xs[2][k];
        a3 += wv * xs[3][k];
    }
    *(f32x4*)&part[w][0][lane * 4] = a0;
    *(f32x4*)&part[w][1][lane * 4] = a1;
    *(f32x4*)&part[w][2][lane * 4] = a2;
    *(f32x4*)&part[w][3][lane * 4] = a3;
    __syncthreads();
    const int c = tid;
    float v[4];
#pragma unroll
    for (int nn = 0; nn < 4; ++nn)
        v[nn] = part[0][nn][c] + part[1][nn][c] + part[2][nn][c] + part[3][nn][c];
    if (ct < 4) {
        float* dst = (ct == 0) ? P : (ct == 1) ? Q : (ct == 2) ? An : Bn;
#pragma unroll
        for (int nn = 0; nn < 4; ++nn) dst[(g * 4 + nn) * 256 + c] = v[nn];
    } else if (ct == 4) {
        if (c < 57) {
#pragma unroll
            for (int nn = 0; nn < 4; ++nn) o_sem[(g * 4 + nn) * 57 + c] = v[nn] + bs[c];
        } else if (c < 67) {
#pragma unroll
            for (int nn = 0; nn < 4; ++nn) o_semins[(g * 4 + nn) * 10 + (c - 57)] = v[nn] + bsi[c - 57];
        } else if (c == 67) {
#pragma unroll
            for (int nn = 0; nn < 4; ++nn) {
                const float e = v[nn] + be[0];
                o_exists[g * 4 + nn] = e;
                ok[g * 4 + nn] = (e > 0.f) ? 1 : 0;
            }
        }
    } else {
        const float gwc = gw[c], gbc = gb[c], bgcc = bgc[c];
#pragma unroll
        for (int nn = 0; nn < 4; ++nn) {
            const float g0 = v[nn] + bgcc;
            float s = g0;
            s += __shfl_xor(s, 1); s += __shfl_xor(s, 2); s += __shfl_xor(s, 4);
            const float m = s * 0.125f;
            const float d = g0 - m;
            float q2 = d * d;
            q2 += __shfl_xor(q2, 1); q2 += __shfl_xor(q2, 2); q2 += __shfl_xor(q2, 4);
            const float var = q2 * 0.125f;
            o_geo[(g * 4 + nn) * 256 + c] = lrelu(d / sqrtf(var + 1e-5f) * gwc + gbc);
        }
    }
}

// ---------------- edge_k: el = lrelu(P_i+Q_j+bel), logits --------------------
__global__ __launch_bounds__(256) void edge_k(
    const float* __restrict__ P, const float* __restrict__ Q,
    const float* __restrict__ bel, const float* __restrict__ Wee,
    const float* __restrict__ bee,
    u16* __restrict__ el, float* __restrict__ o_edge) {
    const int pair = blockIdx.x * 4 + (threadIdx.x >> 6);
    const int l = threadIdx.x & 63;
    const int i = pair >> 7, j = pair & 127;
    f32x4 p = *(const f32x4*)(P + i * 256 + l * 4);
    f32x4 q = *(const f32x4*)(Q + j * 256 + l * 4);
    f32x4 b = *(const f32x4*)(bel + l * 4);
    float e0 = lrelu(p[0] + q[0] + b[0]);
    float e1 = lrelu(p[1] + q[1] + b[1]);
    float e2 = lrelu(p[2] + q[2] + b[2]);
    float e3 = lrelu(p[3] + q[3] + b[3]);
    ushort4 st; st.x = f2bf(e0); st.y = f2bf(e1); st.z = f2bf(e2); st.w = f2bf(e3);
    *(ushort4*)(el + (size_t)pair * 256 + l * 4) = st;
    f32x4 w;
    w = *(const f32x4*)(Wee + 0 * 256 + l * 4);
    float a0 = e0 * w[0] + e1 * w[1] + e2 * w[2] + e3 * w[3];
    w = *(const f32x4*)(Wee + 1 * 256 + l * 4);
    float a1 = e0 * w[0] + e1 * w[1] + e2 * w[2] + e3 * w[3];
    w = *(const f32x4*)(Wee + 2 * 256 + l * 4);
    float a2 = e0 * w[0] + e1 * w[1] + e2 * w[2] + e3 * w[3];
    w = *(const f32x4*)(Wee + 3 * 256 + l * 4);
    float a3 = e0 * w[0] + e1 * w[1] + e2 * w[2] + e3 * w[3];
#pragma unroll
    for (int mk = 1; mk < 64; mk <<= 1) {
        a0 += __shfl_xor(a0, mk); a1 += __shfl_xor(a1, mk);
        a2 += __shfl_xor(a2, mk); a3 += __shfl_xor(a3, mk);
    }
    if (l == 0) {
        f32x4 o;
        o[0] = a0 + bee[0]; o[1] = a1 + bee[1];
        o[2] = a2 + bee[2]; o[3] = a3 + bee[3];
        *(f32x4*)(o_edge + (size_t)pair * 4) = o;
    }
}

// ---------------- mp_k: 2 blocks/node (j-halves), LDS-staged Bn/logits -------
// Partial max over its j-half, clamped at 0, combined via atomicMax on int
// bits (valid: all values >= 0, x slot zero-initialized by stage1_gemv).
__global__ __launch_bounds__(512) void mp_k(
    const u16* __restrict__ el, const float* __restrict__ Anp,
    const float* __restrict__ Bnp, const float* __restrict__ bne_it,
    const u16* __restrict__ W3p_it, const float* __restrict__ W4p_it,
    const float* __restrict__ logits, const int* __restrict__ ok,
    float* __restrict__ xout /* stride 768, zero-init */) {
    const int b = blockIdx.x;
    const int i = b >> 1, jhalf = b & 1;
    if (!ok[i]) return;
    __shared__ float Bs[64 * 260];
    __shared__ float ls[256];
    __shared__ float red[2][4][4][16];
    const int tid = threadIdx.x;
    const int l = tid & 63, wid = tid >> 6;
    const int jh = wid >> 2, hq = wid & 3;
    const int lr = l & 15, lq = l >> 4;
    const int h0 = hq * 64;
    // stage this block's Bn half (64 rows) + logits half into LDS
    for (int idx = tid; idx < 4096; idx += 512) {
        const int j = idx >> 6, c4 = (idx & 63) * 4;
        *(f32x4*)&Bs[j * 260 + c4] =
            *(const f32x4*)(Bnp + (size_t)(jhalf * 64 + j) * 256 + c4);
    }
    if (tid < 256) ls[tid] = logits[(size_t)i * 512 + jhalf * 256 + tid];
    bf16x8 bfr[4][8];
    float an[4], bnev[4];
    f32x4 w4[4];
#pragma unroll
    for (int nt = 0; nt < 4; ++nt) {
#pragma unroll
        for (int ks = 0; ks < 8; ++ks) {
            U8 u;
            u.q = ((const uint4*)W3p_it)[(hq * 4 + nt) * 512 + ks * 64 + l];
            bfr[nt][ks] = u.v;
        }
        const int h = h0 + nt * 16 + lr;
        an[nt] = Anp[i * 256 + h];
        bnev[nt] = bne_it[h];
        w4[nt] = *(const f32x4*)(W4p_it + h * 4);
    }
    unsigned long long bl1 = __ballot(ok[l] != 0);
    unsigned long long bl2 = __ballot(ok[64 + l] != 0);
    unsigned actmask = 0;
#pragma unroll
    for (int jc = 0; jc < 4; ++jc) {
        if ((bl1 >> (jc * 16)) & 0xFFFFull) actmask |= (1u << jc);
        if ((bl2 >> (jc * 16)) & 0xFFFFull) actmask |= (1u << (4 + jc));
    }
    __syncthreads();
    float rm0 = -1e30f, rm1 = -1e30f, rm2 = -1e30f, rm3 = -1e30f;
    const int jc0 = jhalf * 4 + jh * 2;
    for (int jc = jc0; jc < jc0 + 2; ++jc) {
        if (!(actmask & (1u << jc))) continue;
        f32x4 acc0{0.f,0.f,0.f,0.f}, acc1{0.f,0.f,0.f,0.f};
        f32x4 acc2{0.f,0.f,0.f,0.f}, acc3{0.f,0.f,0.f,0.f};
#pragma unroll
        for (int ks = 0; ks < 8; ++ks) {
            U8 u;
            u.q = *(const uint4*)(el + (size_t)(i * 128 + jc * 16 + lr) * 256 + ks * 32 + lq * 8);
            bf16x8 af = u.v;
            acc0 = mfma_(af, bfr[0][ks], acc0);
            acc1 = mfma_(af, bfr[1][ks], acc1);
            acc2 = mfma_(af, bfr[2][ks], acc2);
            acc3 = mfma_(af, bfr[3][ks], acc3);
        }
#pragma unroll
        for (int r = 0; r < 4; ++r) {
            const int j = jc * 16 + lq * 4 + r;
            if (!ok[j]) continue;
            const int jl = j - jhalf * 64;
            f32x4 lg = *(const f32x4*)&ls[jl * 4];
            bool any = (lg[0] > 0.f) | (lg[1] > 0.f) | (lg[2] > 0.f) | (lg[3] > 0.f);
            if (!any) continue;
            const float* bsr = &Bs[jl * 260 + h0 + lr];
            float b0 = bsr[0];
            float b1 = bsr[16];
            float b2 = bsr[32];
            float b3 = bsr[48];
            float amx0 = -1e30f, amx1 = -1e30f, amx2 = -1e30f, amx3 = -1e30f;
#pragma unroll
            for (int t = 0; t < 4; ++t) {
                if (lg[t] > 0.f) {
                    amx0 = fmaxf(amx0, w4[0][t] * lg[t]);
                    amx1 = fmaxf(amx1, w4[1][t] * lg[t]);
                    amx2 = fmaxf(amx2, w4[2][t] * lg[t]);
                    amx3 = fmaxf(amx3, w4[3][t] * lg[t]);
                }
            }
            rm0 = fmaxf(rm0, lrelu(acc0[r] + an[0] + b0 + bnev[0] + amx0));
            rm1 = fmaxf(rm1, lrelu(acc1[r] + an[1] + b1 + bnev[1] + amx1));
            rm2 = fmaxf(rm2, lrelu(acc2[r] + an[2] + b2 + bnev[2] + amx2));
            rm3 = fmaxf(rm3, lrelu(acc3[r] + an[3] + b3 + bnev[3] + amx3));
        }
    }
    rm0 = fmaxf(rm0, __shfl_xor(rm0, 16)); rm0 = fmaxf(rm0, __shfl_xor(rm0, 32));
    rm1 = fmaxf(rm1, __shfl_xor(rm1, 16)); rm1 = fmaxf(rm1, __shfl_xor(rm1, 32));
    rm2 = fmaxf(rm2, __shfl_xor(rm2, 16)); rm2 = fmaxf(rm2, __shfl_xor(rm2, 32));
    rm3 = fmaxf(rm3, __shfl_xor(rm3, 16)); rm3 = fmaxf(rm3, __shfl_xor(rm3, 32));
    if (lq == 0) {
        red[jh][hq][0][lr] = rm0;
        red[jh][hq][1][lr] = rm1;
        red[jh][hq][2][lr] = rm2;
        red[jh][hq][3][lr] = rm3;
    }
    __syncthreads();
    if (jh == 0 && lq == 0) {
#pragma unroll
        for (int nt = 0; nt < 4; ++nt) {
            float v = fmaxf(fmaxf(red[0][hq][nt][lr], red[1][hq][nt][lr]), 0.f);
            atomicMax((int*)&xout[i * 768 + h0 + nt * 16 + lr], __float_as_int(v));
        }
    }
}

// ---------------- node_gemv: An1/Bn1 from x1 (split-K) -----------------------
__global__ __launch_bounds__(256) void node_gemv(
    const float* __restrict__ cat, const float* __restrict__ WT_n,
    float* __restrict__ An, float* __restrict__ Bn) {
    const int ct = blockIdx.x & 1, g = blockIdx.x >> 1;
    const int tid = threadIdx.x, lane = tid & 63, w = tid >> 6;
    __shared__ float xs[4][256];
    __shared__ float part[4][4][256];
    for (int idx = tid; idx < 1024; idx += 256) {
        const int nn = idx >> 8, k = idx & 255;
        xs[nn][k] = cat[(g * 4 + nn) * 768 + 256 + k];
    }
    __syncthreads();
    f32x4 a0{0,0,0,0}, a1{0,0,0,0}, a2{0,0,0,0}, a3{0,0,0,0};
    const float* wp = WT_n + (size_t)(w * 64) * 512 + ct * 256 + lane * 4;
#pragma unroll 4
    for (int kk = 0; kk < 64; ++kk) {
        const int k = w * 64 + kk;
        f32x4 wv = *(const f32x4*)wp; wp += 512;
        a0 += wv * xs[0][k];
        a1 += wv * xs[1][k];
        a2 += wv * xs[2][k];
        a3 += wv * xs[3][k];
    }
    *(f32x4*)&part[w][0][lane * 4] = a0;
    *(f32x4*)&part[w][1][lane * 4] = a1;
    *(f32x4*)&part[w][2][lane * 4] = a2;
    *(f32x4*)&part[w][3][lane * 4] = a3;
    __syncthreads();
    const int c = tid;
    float* dst = ct ? Bn : An;
#pragma unroll
    for (int nn = 0; nn < 4; ++nn)
        dst[(g * 4 + nn) * 256 + c] = part[0][nn][c] + part[1][nn][c] + part[2][nn][c] + part[3][nn][c];
}

// ---------------- head_gemv: fused 2-layer head, split-K ---------------------
__global__ __launch_bounds__(256) void head_gemv(
    const float* __restrict__ cat, const float* __restrict__ WT_c,
    const float* __restrict__ bc, const float* __restrict__ WT_c2,
    const float* __restrict__ bc2, float* __restrict__ o_child) {
    const int i = blockIdx.x;
    const int tid = threadIdx.x, lane = tid & 63, w = tid >> 6;
    __shared__ float xs[768];
    __shared__ float part[4][256];
    __shared__ float ch[256];
    for (int idx = tid; idx < 768; idx += 256) xs[idx] = cat[i * 768 + idx];
    __syncthreads();
    f32x4 acc{0,0,0,0};
    const float* wp = WT_c + (size_t)(w * 192) * 256 + lane * 4;
#pragma unroll 4
    for (int kk = 0; kk < 192; ++kk) {
        f32x4 wv = *(const f32x4*)wp; wp += 256;
        acc += wv * xs[w * 192 + kk];
    }
    *(f32x4*)&part[w][lane * 4] = acc;
    __syncthreads();
    ch[tid] = lrelu(part[0][tid] + part[1][tid] + part[2][tid] + part[3][tid] + bc[tid]);
    __syncthreads();
    f32x4 acc2{0,0,0,0};
    wp = WT_c2 + (size_t)(w * 64) * 256 + lane * 4;
#pragma unroll 4
    for (int kk = 0; kk < 64; ++kk) {
        f32x4 wv = *(const f32x4*)wp; wp += 256;
        acc2 += wv * ch[w * 64 + kk];
    }
    __syncthreads();
    *(f32x4*)&part[w][lane * 4] = acc2;
    __syncthreads();
    o_child[i * 256 + tid] = lrelu(part[0][tid] + part[1][tid] + part[2][tid] + part[3][tid] + bc2[tid]);
}

extern "C" void kernel_launch(void* const* d_in, const int* in_sizes, int n_in,
                              void* d_out, int out_size, void* d_ws, size_t ws_size,
                              hipStream_t stream) {
    (void)in_sizes; (void)n_in; (void)out_size; (void)ws_size;
    const float* psf = (const float*)d_in[0];
    const float* pgf = (const float*)d_in[1];
    const float* Wp  = (const float*)d_in[2];
    const float* bp  = (const float*)d_in[3];
    const float* We  = (const float*)d_in[4];
    const float* be  = (const float*)d_in[5];
    const float* Ws  = (const float*)d_in[6];
    const float* bs  = (const float*)d_in[7];
    const float* Wsi = (const float*)d_in[8];
    const float* bsi = (const float*)d_in[9];
    const float* Wel = (const float*)d_in[10];
    const float* bel = (const float*)d_in[11];
    const float* Wee = (const float*)d_in[12];
    const float* bee = (const float*)d_in[13];
    const float* Wne = (const float*)d_in[14];
    const float* bne = (const float*)d_in[15];
    const float* Wc  = (const float*)d_in[16];
    const float* bc  = (const float*)d_in[17];
    const float* Wc2 = (const float*)d_in[18];
    const float* bc2 = (const float*)d_in[19];
    const float* Wgc = (const float*)d_in[20];
    const float* bgc = (const float*)d_in[21];
    const float* Wgp = (const float*)d_in[22];
    const float* bgp = (const float*)d_in[23];
    const float* gw  = (const float*)d_in[24];
    const float* gb  = (const float*)d_in[25];

    float* ws   = (float*)d_ws;
    float* pg   = ws;                    // 32768
    float* cat  = ws + 32768;            // 98304 (128 x 768: x0|x1|x2)
    float* P    = ws + 131072;           // 32768 (An1 after edge_k)
    float* Q    = ws + 163840;           // 32768 (Bn1 after edge_k)
    float* An   = ws + 196608;           // 32768
    float* Bn   = ws + 229376;           // 32768
    int*   ok   = (int*)(ws + 262144);   // 128
    u16*   el   = (u16*)(ws + 262272);   // 16384x256 bf16
    u16*   W3p  = (u16*)(ws + 2359424);  // 2 x 65536 u16
    float* WT_a = ws + 2424960;          // 256 x 1280
    float* WT_g = ws + 2752640;          // 256 x 256
    float* WT_n = ws + 2818176;          // 256 x 512
    float* WT_c = ws + 2949248;          // 768 x 256
    float* WT_c2= ws + 3145856;          // 256 x 256
    float* W4p  = ws + 3211392;          // 2 x 1024
    float* An1  = P;
    float* Bn1  = Q;

    float* out = (float*)d_out;
    float* o_child  = out;
    float* o_geo    = out + 32768;
    float* o_sem    = out + 65536;
    float* o_semins = out + 72832;
    float* o_exists = out + 74112;
    float* o_edge   = out + 74240;

    pack_all<<<258, 256, 0, stream>>>(Wel, Wne, Ws, Wsi, We, Wgc, Wc, Wc2,
                                      WT_a, WT_g, WT_n, WT_c, WT_c2, W3p, W4p);
    big_matvec<<<2048, 256, 0, stream>>>(Wp, bp, Wgp, bgp, psf, pgf, cat, pg);
    stage1_gemv<<<192, 256, 0, stream>>>(cat, cat, pg, WT_a, WT_g, bgc, gw, gb,
                                         be, bs, bsi, P, Q, An, Bn, ok,
                                         o_geo, o_sem, o_semins, o_exists);
    edge_k<<<4096, 256, 0, stream>>>(P, Q, bel, Wee, bee, el, o_edge);
    mp_k<<<256, 512, 0, stream>>>(el, An, Bn, bne, W3p, W4p,
                                  o_edge, ok, cat + 256);
    node_gemv<<<64, 256, 0, stream>>>(cat, WT_n, An1, Bn1);
    mp_k<<<256, 512, 0, stream>>>(el, An1, Bn1, bne + 256, W3p + 65536,
                                  W4p + 1024, o_edge, ok, cat + 512);
    head_gemv<<<128, 256, 0, stream>>>(cat, WT_c, bc, WT_c2, bc2, o_child);
}